// Round 14
// baseline (790.356 us; speedup 1.0000x reference)
//
#include <hip/hip_runtime.h>
#include <hip/hip_bf16.h>

typedef __hip_bfloat16 bf16;
typedef __attribute__((ext_vector_type(8))) short bfrag8;   // 8 bf16 (4 VGPR) MFMA A/B frag
typedef __attribute__((ext_vector_type(4))) float facc4;    // MFMA C/D frag
typedef __attribute__((ext_vector_type(4))) unsigned short us4;
typedef __attribute__((ext_vector_type(8))) unsigned short us8;
typedef __attribute__((ext_vector_type(4))) float f32x4;    // true clang vector (for nontemporal)

#define AS1C const __attribute__((address_space(1))) void
#define AS3  __attribute__((address_space(3))) void

__device__ __forceinline__ void gload_lds16(const void* src, void* dst) {
    __builtin_amdgcn_global_load_lds((AS1C*)src, (AS3*)dst, 16, 0, 0);
}

__device__ __forceinline__ unsigned short f2bf(float f) {   // RNE, finite inputs
    unsigned u = __float_as_uint(f);
    unsigned r = u + 0x7FFFu + ((u >> 16) & 1u);
    return (unsigned short)(r >> 16);
}
__device__ __forceinline__ float bf2f(unsigned short u) {   // exact
    return __uint_as_float((unsigned)u << 16);
}

// ------- merged prep+cvt: weights first (heavy), DENSE vectorized tail -------
__global__ void prep_cvt_kernel(const float* __restrict__ input, const float* __restrict__ targets,
                                const float* __restrict__ sos, const float* __restrict__ W_emb,
                                const float* __restrict__ Wm, const float* __restrict__ Wpi_m,
                                const float* __restrict__ Wmu_m, const float* __restrict__ Wsg_m,
                                const float* __restrict__ Wpi_v, const float* __restrict__ Wmu_v,
                                const float* __restrict__ Wsg_v,
                                const float* __restrict__ bm, const float* __restrict__ bpi_m,
                                const float* __restrict__ bmu_m, const float* __restrict__ bsg_m,
                                const float* __restrict__ bpi_v, const float* __restrict__ bmu_v,
                                const float* __restrict__ bsg_v,
                                const float* __restrict__ Wqkv, const float* __restrict__ Wo,
                                const float* __restrict__ W1, const float* __restrict__ W2,
                                float* __restrict__ pe, bf16* __restrict__ xin,
                                bf16* __restrict__ wemb, bf16* __restrict__ whead,
                                float* __restrict__ bhead,
                                bf16* __restrict__ wqb, bf16* __restrict__ wob,
                                bf16* __restrict__ w1b, bf16* __restrict__ w2b) {
    int bid = blockIdx.x;
    int t = threadIdx.x;
    if (bid < 4608) {                                    // weight cvt (NT loads, NT 16B stores)
        int l = bid / 768;
        int s = bid - l * 768;
        const float* src; bf16* dst;
        if (s < 384)      { src = Wqkv + (size_t)l * 3145728; dst = wqb + (size_t)l * 3145728; }
        else if (s < 512) { src = Wo + (size_t)l * 1048576; dst = wob + (size_t)l * 1048576; s -= 384; }
        else if (s < 640) { src = W1 + (size_t)l * 1048576; dst = w1b + (size_t)l * 1048576; s -= 512; }
        else              { src = W2 + (size_t)l * 1048576; dst = w2b + (size_t)l * 1048576; s -= 640; }
        size_t pbase = (size_t)s * 1024 + t;
#pragma unroll
        for (int it = 0; it < 4; ++it) {
            size_t o = (pbase + it * 256) * 8;           // 8 floats per pair
            const f32x4* p = (const f32x4*)(src + o);
            f32x4 v1 = __builtin_nontemporal_load(p);
            f32x4 v2 = __builtin_nontemporal_load(p + 1);
            us8 w8;
            w8[0] = f2bf(v1.x); w8[1] = f2bf(v1.y); w8[2] = f2bf(v1.z); w8[3] = f2bf(v1.w);
            w8[4] = f2bf(v2.x); w8[5] = f2bf(v2.y); w8[6] = f2bf(v2.z); w8[7] = f2bf(v2.w);
            __builtin_nontemporal_store(w8, (us8*)(dst + o));
        }
    } else if (bid < 4736) {                             // pe [128][1024]
        int s = bid - 4608;
        float4 v;
#pragma unroll
        for (int j = 0; j < 4; ++j) {
            int c = t * 4 + j;
            int i = c >> 1;
            float div = expf(-9.210340371976184f * (float)(2 * i) * (1.f / 1024.f));
            float a = (float)s * div;
            v[j] = (c & 1) ? cosf(a) : sinf(a);
        }
        *(float4*)(pe + (size_t)s * 1024 + t * 4) = v;
    } else if (bid < 5888) {                             // xin: 294912 us8-chunks (4096 rows x 72)
        int chunk = (bid - 4736) * 256 + t;
        int row = chunk / 72;
        int cc = chunk - row * 72;
        int b = row >> 7, s = row & 127;
        us8 w8;
        if (cc < 64) {
            const float* p = input + (size_t)b * 512 + cc * 8;
            float4 v1 = *(const float4*)p;
            float4 v2 = *(const float4*)(p + 4);
            w8[0] = f2bf(v1.x); w8[1] = f2bf(v1.y); w8[2] = f2bf(v1.z); w8[3] = f2bf(v1.w);
            w8[4] = f2bf(v2.x); w8[5] = f2bf(v2.y); w8[6] = f2bf(v2.z); w8[7] = f2bf(v2.w);
        } else {
#pragma unroll
            for (int j = 0; j < 8; ++j) {
                int col = cc * 8 + j;
                float v = 0.f;
                if (col < 545) {
                    int jj = col - 512;
                    v = (s == 0) ? sos[jj] : targets[((size_t)b * 127 + (s - 1)) * 33 + jj];
                }
                w8[j] = f2bf(v);
            }
        }
        *(us8*)(xin + (size_t)row * 576 + cc * 8) = w8;
    } else if (bid < 6176) {                             // wemb: pad 545->576
        int chunk = (bid - 5888) * 256 + t;
        int row = chunk / 72;
        int cc = chunk - row * 72;
        us8 w8;
#pragma unroll
        for (int j = 0; j < 8; ++j) {
            int col = cc * 8 + j;
            w8[j] = f2bf(col < 545 ? W_emb[(size_t)row * 545 + col] : 0.f);
        }
        *(us8*)(wemb + (size_t)row * 576 + cc * 8) = w8;
    } else if (bid < 6496) {                             // whead: 640 rows x 128 chunks
        int chunk = (bid - 6176) * 256 + t;
        int r = chunk >> 7;
        int cc = chunk & 127;
        const float* wsrc = nullptr; int off = 0;
        if (r == 0)        { wsrc = Wm;    off = 0; }
        else if (r < 9)    { wsrc = Wpi_m; off = r - 1; }
        else if (r < 137)  { wsrc = Wmu_m; off = r - 9; }
        else if (r < 265)  { wsrc = Wsg_m; off = r - 137; }
        else if (r < 273)  { wsrc = Wpi_v; off = r - 265; }
        else if (r < 401)  { wsrc = Wmu_v; off = r - 273; }
        else if (r < 529)  { wsrc = Wsg_v; off = r - 401; }
        us8 w8;
        if (wsrc) {
            const float* p = wsrc + (size_t)off * 1024 + cc * 8;
            float4 v1 = *(const float4*)p;
            float4 v2 = *(const float4*)(p + 4);
            w8[0] = f2bf(v1.x); w8[1] = f2bf(v1.y); w8[2] = f2bf(v1.z); w8[3] = f2bf(v1.w);
            w8[4] = f2bf(v2.x); w8[5] = f2bf(v2.y); w8[6] = f2bf(v2.z); w8[7] = f2bf(v2.w);
        } else {
#pragma unroll
            for (int j = 0; j < 8; ++j) w8[j] = 0;
        }
        *(us8*)(whead + (size_t)r * 1024 + cc * 8) = w8;
    } else {                                             // bhead: 529 scalars
        if (t < 529) {
            const float* bsrc; int off;
            if (t == 0)       { bsrc = bm;    off = 0; }
            else if (t < 9)   { bsrc = bpi_m; off = t - 1; }
            else if (t < 137) { bsrc = bmu_m; off = t - 9; }
            else if (t < 265) { bsrc = bsg_m; off = t - 137; }
            else if (t < 273) { bsrc = bpi_v; off = t - 265; }
            else if (t < 401) { bsrc = bmu_v; off = t - 273; }
            else              { bsrc = bsg_v; off = t - 401; }
            bhead[t] = bsrc[off];
        }
    }
}

// ---------------- main GEMM: C[M,N] = A[M,K] @ B[N,K]^T (+epilogue) ----------------
// 128x128 tile. Operand-swapped MFMA (C^T frags -> vectorized epilogue).
// XCD-chunked blockIdx swizzle (T1, bijective; applied when nwg%8==0).
// CFG=0: 256t, BK=64, single-buffer, 4 blocks/CU -- big grids (QKV).
// CFG=1: 512t, BK=64, dbuf(__syncthreads) -- grid-limited, K%128!=0 (embed).
// CFG=2: 512t, BK=128, dbuf + COUNTED vmcnt(8) pipeline (raw s_barrier, NO
//        sched_barriers -- round-6's regression was m141 pinning from those;
//        gload_lds/LDS-loads are IR memory ops ordered by the "memory" clobber,
//        so rule-#18's fence is not needed here). Loads for tile t+1 stay in
//        flight across the barrier; only tile t's 8 retire per wait.
// EPI: 0 bias->bf16 | 1 bias+relu->bf16 | 3 bias->f32 scalar (odd ldc) | 4 bias+pe->bf16
template<int EPI, int CFG>
__global__ __launch_bounds__(CFG ? 512 : 256, CFG ? 2 : 4) void gemm_bt(
    const bf16* __restrict__ A, const bf16* __restrict__ Bw,
    float* __restrict__ Cf, bf16* __restrict__ Cb,
    const float* __restrict__ bias, const float* __restrict__ pe,
    int M, int N, int K, int lda, int ldb, int ldc, long long Az, long long Cz)
{
    constexpr int NT  = CFG ? 512 : 256;    // threads
    constexpr int NB  = CFG ? 2 : 1;        // LDS buffers
    constexpr int MI  = CFG ? 2 : 4;        // per-wave M fragments
    constexpr int BK  = (CFG == 2) ? 128 : 64;
    constexpr int RB  = BK * 2;             // row bytes in LDS
    constexpr int CPR = BK / 8;             // 16B chunks per row
    constexpr int NCH = (128 * CPR) / NT;   // staging chunks per thread per array
    constexpr int KS  = BK / 32;            // 32-wide k-slices per tile
    __shared__ __align__(16) bf16 sA[NB][128 * BK];
    __shared__ __align__(16) bf16 sB[NB][128 * BK];
    const int t = threadIdx.x;
    const int w = t >> 6, la = t & 63;
    const int wm = CFG ? (w >> 1) * 32 : (w >> 1) * 64;
    const int wn = (w & 1) * 64;
    // XCD-chunked swizzle (identity when nwg not divisible by 8, e.g. heads grid)
    int nwgxy = gridDim.x * gridDim.y;
    int flat = blockIdx.y * gridDim.x + blockIdx.x;
    if ((nwgxy & 7) == 0) {
        int cpx = nwgxy >> 3;
        flat = (flat & 7) * cpx + (flat >> 3);
    }
    const int m0 = (flat / gridDim.x) * 128, n0 = (flat % gridDim.x) * 128;
    const int z = blockIdx.z;
    A += (long long)z * Az;

    facc4 zero4 = {0.f, 0.f, 0.f, 0.f};
    facc4 acc[MI][4];
#pragma unroll
    for (int mi = 0; mi < MI; ++mi)
#pragma unroll
        for (int ni = 0; ni < 4; ++ni) acc[mi][ni] = zero4;

    auto stage = [&](int buf, int kt) {                 // 2*NCH gload_lds per call
#pragma unroll
        for (int i = 0; i < NCH; ++i) {
            int c = i * NT + t;
            int r = c / CPR;
            int cc = c - r * CPR;
            int bc = (cc * 16) ^ ((r & 7) << 4);        // pre-swizzled source byte col
            gload_lds16(A + (size_t)(m0 + r) * lda + kt + (bc >> 1),
                        (char*)sA[buf] + (size_t)c * 16);
            gload_lds16(Bw + (size_t)(n0 + r) * ldb + kt + (bc >> 1),
                        (char*)sB[buf] + (size_t)c * 16);
        }
    };
    auto compute = [&](int buf) {
#pragma unroll
        for (int ks = 0; ks < KS; ++ks) {
            bfrag8 af[MI], bfv[4];
            const int koffb = (ks * 32 + (la >> 4) * 8) * 2;
#pragma unroll
            for (int i = 0; i < MI; ++i) {
                int rowa = wm + i * 16 + (la & 15);
                af[i] = *(const bfrag8*)((const char*)sA[buf] + rowa * RB + (koffb ^ ((rowa & 7) << 4)));
            }
#pragma unroll
            for (int i = 0; i < 4; ++i) {
                int rowb = wn + i * 16 + (la & 15);
                bfv[i] = *(const bfrag8*)((const char*)sB[buf] + rowb * RB + (koffb ^ ((rowb & 7) << 4)));
            }
#pragma unroll
            for (int mi = 0; mi < MI; ++mi)
#pragma unroll
                for (int ni = 0; ni < 4; ++ni)     // swapped operands -> C^T fragment
                    acc[mi][ni] = __builtin_amdgcn_mfma_f32_16x16x32_bf16(bfv[ni], af[mi], acc[mi][ni], 0, 0, 0);
        }
    };

    const int nk = K / BK;
    if constexpr (CFG == 2) {
        // counted-vmcnt 2-deep pipeline: 16 loads in flight, vmcnt(8) retires
        // exactly tile-t's 8 (wait counts OLDEST outstanding). barrier2 +
        // per-wave data dependence (MFMA needs its ds_reads) makes stage(t+2)'s
        // overwrite of buf t&1 race-free.
        stage(0, 0);
        if (nk > 1) stage(1, BK);
        for (int kt = 0; kt < nk; ++kt) {
            if (kt + 1 < nk) { asm volatile("s_waitcnt vmcnt(8)" ::: "memory"); }
            else             { asm volatile("s_waitcnt vmcnt(0)" ::: "memory"); }
            __builtin_amdgcn_s_barrier();               // tile kt resident for all waves
            compute(kt & 1);
            __builtin_amdgcn_s_barrier();               // all waves done reading buf kt&1
            if (kt + 2 < nk) stage(kt & 1, (kt + 2) * BK);
        }
    } else if constexpr (CFG == 1) {
        stage(0, 0);
        __syncthreads();
        int cur = 0;
        for (int kt = 0; kt < nk; ++kt) {
            if (kt + 1 < nk) stage(cur ^ 1, (kt + 1) * BK);
            compute(cur);
            __syncthreads();        // drains stage(k+1) vmcnt; frees cur
            cur ^= 1;
        }
    } else {
        for (int kt = 0; kt < nk; ++kt) {
            stage(0, kt * BK);
            __syncthreads();
            compute(0);
            __syncthreads();
        }
    }
    // epilogue: thread holds C[row][colb..colb+3]
#pragma unroll
    for (int mi = 0; mi < MI; ++mi) {
        int row = m0 + wm + mi * 16 + (la & 15);
#pragma unroll
        for (int ni = 0; ni < 4; ++ni) {
            int colb = n0 + wn + ni * 16 + (la >> 4) * 4;
            if constexpr (EPI == 3) {               // scalar path (odd ldc / edge guards)
                if (row >= M) continue;
#pragma unroll
                for (int j = 0; j < 4; ++j) {
                    int col = colb + j;
                    if (col < N)
                        Cf[(size_t)z * Cz + (size_t)row * ldc + col] = acc[mi][ni][j] + bias[col];
                }
            } else {
                float4 bv = *(const float4*)(bias + colb);
                facc4 v = acc[mi][ni];
                v[0] += bv.x; v[1] += bv.y; v[2] += bv.z; v[3] += bv.w;
                size_t cidx = (size_t)row * ldc + colb;
                if constexpr (EPI == 0) {
                    us4 o; o.x = f2bf(v[0]); o.y = f2bf(v[1]); o.z = f2bf(v[2]); o.w = f2bf(v[3]);
                    *(us4*)(Cb + cidx) = o;
                } else if constexpr (EPI == 1) {
                    us4 o;
                    o.x = f2bf(v[0] > 0.f ? v[0] : 0.f); o.y = f2bf(v[1] > 0.f ? v[1] : 0.f);
                    o.z = f2bf(v[2] > 0.f ? v[2] : 0.f); o.w = f2bf(v[3] > 0.f ? v[3] : 0.f);
                    *(us4*)(Cb + cidx) = o;
                } else {                            // EPI == 4: bias + pe -> bf16
                    float4 p = *(const float4*)(pe + (size_t)(row & 127) * 1024 + colb);
                    us4 o;
                    o.x = f2bf(v[0] + p.x); o.y = f2bf(v[1] + p.y);
                    o.z = f2bf(v[2] + p.z); o.w = f2bf(v[3] + p.w);
                    *(us4*)(Cb + cidx) = o;
                }
            }
        }
    }
}

// ---------------- fused attention: one block per (b,h) ----------------
// S=128, D=64. Q in registers; K, V^T in LDS. In-register one-pass causal softmax.
// setprio(1) around MFMA clusters (T5).
__global__ __launch_bounds__(256) void attn_fused(const bf16* __restrict__ qkv, bf16* __restrict__ obf)
{
    __shared__ __align__(16) char lds[65536];
    char* sK  = lds + 16384;    // [128] rows x 128B, swizzled (dead after QK^T -> red arrays)
    char* sS  = lds + 32768;    // [128] rows x 256B bf16 (P)
    char* sVT = lds;            // [64] rows x 256B (V transposed)
    float* redm = (float*)(lds + 16384);            // [2][128] row max per col-half
    float* reds = (float*)(lds + 16384 + 1024);     // [2][128] row exp-sum per col-half

    const int t = threadIdx.x, w = t >> 6, la = t & 63;
    const int b = blockIdx.x >> 4, h = blockIdx.x & 15;
    const size_t base = (size_t)b * 128 * 3072 + (size_t)h * 64;

    const int wm = (w >> 1) * 64, wn = (w & 1) * 64;

    // phase 1: stage K into LDS; load Q fragments straight to registers
#pragma unroll
    for (int i = 0; i < 4; ++i) {
        int c = i * 256 + w * 64 + la;
        int r = c >> 3;
        int bc = ((c & 7) * 16) ^ ((r & 7) << 4);
        gload_lds16(qkv + base + 1024 + (size_t)r * 3072 + (bc >> 1),
                    sK + (size_t)(i * 256 + w * 64) * 16);
    }
    bfrag8 qf[4][2];
#pragma unroll
    for (int mi = 0; mi < 4; ++mi)
#pragma unroll
        for (int ks = 0; ks < 2; ++ks) {
            int rowa = wm + mi * 16 + (la & 15);
            int k0 = ks * 32 + (la >> 4) * 8;
            qf[mi][ks] = *(const bfrag8*)(qkv + base + (size_t)rowa * 3072 + k0);
        }
    __syncthreads();

    // phase 2: S = Q K^T (swapped mfma -> thread holds S[q][kb..kb+3], fp32)
    facc4 zero4 = {0.f, 0.f, 0.f, 0.f};
    facc4 acc[4][4];
#pragma unroll
    for (int mi = 0; mi < 4; ++mi)
#pragma unroll
        for (int ni = 0; ni < 4; ++ni) acc[mi][ni] = zero4;
    __builtin_amdgcn_s_setprio(1);
#pragma unroll
    for (int ks = 0; ks < 2; ++ks) {
        bfrag8 bfv[4];
        const int koffb = (ks * 32 + (la >> 4) * 8) * 2;
#pragma unroll
        for (int i = 0; i < 4; ++i) {
            int rowb = wn + i * 16 + (la & 15);
            bfv[i] = *(const bfrag8*)(sK + rowb * 128 + (koffb ^ ((rowb & 7) << 4)));
        }
#pragma unroll
        for (int mi = 0; mi < 4; ++mi)
#pragma unroll
            for (int ni = 0; ni < 4; ++ni)
                acc[mi][ni] = __builtin_amdgcn_mfma_f32_16x16x32_bf16(bfv[ni], qf[mi][ks], acc[mi][ni], 0, 0, 0);
    }
    __builtin_amdgcn_s_setprio(0);
    __syncthreads();        // all waves done reading sK

    // phase 3a: stage V transposed into sVT (overlaps softmax VALU below)
#pragma unroll
    for (int i = 0; i < 4; ++i) {
        int c = i * 256 + t;
        int r = c >> 3;             // key index s'
        int d0 = (c & 7) * 8;
        bfrag8 vv = *(const bfrag8*)(qkv + base + 2048 + (size_t)r * 3072 + d0);
#pragma unroll
        for (int j = 0; j < 8; ++j) {
            int d = d0 + j;
            *(short*)(sVT + d * 256 + ((2 * r) ^ ((d & 7) << 4))) = vv[j];
        }
    }

    // phase 3b: in-register causal softmax (one sweep per half)
    const int colh = (w & 1) * 128;
    float tmpm[4], tmps[4];
#pragma unroll
    for (int mi = 0; mi < 4; ++mi) {
        int q = wm + mi * 16 + (la & 15);
        float mx = -1e30f;
#pragma unroll
        for (int ni = 0; ni < 4; ++ni) {
            int kb = wn + ni * 16 + (la >> 4) * 4;
#pragma unroll
            for (int j = 0; j < 4; ++j) {
                float s = acc[mi][ni][j] * 0.125f;
                acc[mi][ni][j] = s;
                if (kb + j <= q) mx = fmaxf(mx, s);
            }
        }
        mx = fmaxf(mx, __shfl_xor(mx, 16));     // reduce over la>>4 (the k-axis lanes)
        mx = fmaxf(mx, __shfl_xor(mx, 32));
        float sm = 0.f;
#pragma unroll
        for (int ni = 0; ni < 4; ++ni) {
            int kb = wn + ni * 16 + (la >> 4) * 4;
#pragma unroll
            for (int j = 0; j < 4; ++j) {
                float e = (kb + j <= q) ? __expf(acc[mi][ni][j] - mx) : 0.f;
                acc[mi][ni][j] = e;
                sm += e;
            }
        }
        sm += __shfl_xor(sm, 16);
        sm += __shfl_xor(sm, 32);
        tmpm[mi] = mx; tmps[mi] = sm;
    }
    if ((la >> 4) == 0) {
#pragma unroll
        for (int mi = 0; mi < 4; ++mi) {
            redm[colh + wm + mi * 16 + la] = tmpm[mi];
            reds[colh + wm + mi * 16 + la] = tmps[mi];
        }
    }
    __syncthreads();
#pragma unroll
    for (int mi = 0; mi < 4; ++mi) {            // combine halves, normalize, pack P -> sS
        int q = wm + mi * 16 + (la & 15);
        float m0 = redm[q], m1 = redm[128 + q];
        float M = fmaxf(m0, m1);
        float tot = reds[q] * __expf(m0 - M) + reds[128 + q] * __expf(m1 - M);
        float sc = __expf(tmpm[mi] - M) / tot;
#pragma unroll
        for (int ni = 0; ni < 4; ++ni) {
            int kb = wn + ni * 16 + (la >> 4) * 4;
            us4 sv;
            sv.x = f2bf(acc[mi][ni][0] * sc); sv.y = f2bf(acc[mi][ni][1] * sc);
            sv.z = f2bf(acc[mi][ni][2] * sc); sv.w = f2bf(acc[mi][ni][3] * sc);
            *(us4*)(sS + q * 256 + ((2 * kb) ^ ((q & 7) << 4))) = sv;
        }
    }
    __syncthreads();                             // sS + sVT complete before PV

    // phase 4: O = P V  (wave tile 64M x 32N, K=128; swapped mfma -> packed O stores)
    const int wm2 = (w >> 1) * 64, wn2 = (w & 1) * 32;
    facc4 a2[4][2];
#pragma unroll
    for (int mi = 0; mi < 4; ++mi) { a2[mi][0] = zero4; a2[mi][1] = zero4; }
    __builtin_amdgcn_s_setprio(1);
#pragma unroll
    for (int ks = 0; ks < 4; ++ks) {
        bfrag8 pa[4], vb[2];
        const int koffb = (ks * 32 + (la >> 4) * 8) * 2;
#pragma unroll
        for (int mi = 0; mi < 4; ++mi) {
            int rowa = wm2 + mi * 16 + (la & 15);
            pa[mi] = *(const bfrag8*)(sS + rowa * 256 + (koffb ^ ((rowa & 7) << 4)));
        }
#pragma unroll
        for (int ni = 0; ni < 2; ++ni) {
            int rowb = wn2 + ni * 16 + (la & 15);
            vb[ni] = *(const bfrag8*)(sVT + rowb * 256 + (koffb ^ ((rowb & 7) << 4)));
        }
#pragma unroll
        for (int mi = 0; mi < 4; ++mi)
#pragma unroll
            for (int ni = 0; ni < 2; ++ni)
                a2[mi][ni] = __builtin_amdgcn_mfma_f32_16x16x32_bf16(vb[ni], pa[mi], a2[mi][ni], 0, 0, 0);
    }
    __builtin_amdgcn_s_setprio(0);
#pragma unroll
    for (int mi = 0; mi < 4; ++mi) {
        int s = wm2 + mi * 16 + (la & 15);
#pragma unroll
        for (int ni = 0; ni < 2; ++ni) {
            int db = wn2 + ni * 16 + (la >> 4) * 4;
            us4 ov;
            ov.x = f2bf(a2[mi][ni][0]); ov.y = f2bf(a2[mi][ni][1]);
            ov.z = f2bf(a2[mi][ni][2]); ov.w = f2bf(a2[mi][ni][3]);
            *(us4*)(obf + ((size_t)(b * 128 + s)) * 1024 + h * 64 + db) = ov;
        }
    }
}

// ------- fused residual + LayerNorm, all-bf16 stream: t = res + go; LN(t) -> xb -------
// 2 rows per block, 16B us8 I/O. In-place res==xb_out safe (element-owned).
__global__ __launch_bounds__(256) void ln_res_kernel(const bf16* __restrict__ go,
                                                     const bf16* __restrict__ res,
                                                     const float* __restrict__ g, const float* __restrict__ be,
                                                     bf16* __restrict__ xb_out)
{
    const int t = threadIdx.x;
    const int row = blockIdx.x * 2 + (t >> 7);   // 2 rows/block, 128 threads (2 waves) each
    const int ct = t & 127;
    size_t o = (size_t)row * 1024 + ct * 8;
    us8 gv8 = *(const us8*)(go + o);
    us8 rv8 = *(const us8*)(res + o);
    float v[8];
    float s = 0.f, q = 0.f;
#pragma unroll
    for (int j = 0; j < 8; ++j) {
        v[j] = bf2f(rv8[j]) + bf2f(gv8[j]);
        s += v[j];
        q += v[j] * v[j];
    }
#pragma unroll
    for (int off = 32; off; off >>= 1) {
        s += __shfl_xor(s, off);
        q += __shfl_xor(q, off);
    }
    __shared__ float ssum[4], sqs[4];
    if ((t & 63) == 0) { ssum[t >> 6] = s; sqs[t >> 6] = q; }
    __syncthreads();
    int rb = (t >> 7) * 2;
    s = ssum[rb] + ssum[rb + 1];
    q = sqs[rb] + sqs[rb + 1];
    float mean = s * (1.f / 1024.f);
    float var = q * (1.f / 1024.f) - mean * mean;
    float rstd = rsqrtf(var + 1e-5f);
    float4 g1v = *(const float4*)(g + ct * 8);
    float4 g2v = *(const float4*)(g + ct * 8 + 4);
    float4 b1v = *(const float4*)(be + ct * 8);
    float4 b2v = *(const float4*)(be + ct * 8 + 4);
    float ga[8] = {g1v.x, g1v.y, g1v.z, g1v.w, g2v.x, g2v.y, g2v.z, g2v.w};
    float ba[8] = {b1v.x, b1v.y, b1v.z, b1v.w, b2v.x, b2v.y, b2v.z, b2v.w};
    us8 ob;
#pragma unroll
    for (int j = 0; j < 8; ++j)
        ob[j] = f2bf((v[j] - mean) * rstd * ga[j] + ba[j]);
    *(us8*)(xb_out + o) = ob;
}

// ---------------- MDN finalize / scatter ----------------
__global__ void finalize_kernel(const float* __restrict__ hout, float* __restrict__ out) {
    const size_t O_PI_M = 0, O_MU_M = 32512, O_VAR_M = 552704, O_PI_V = 1072896,
                 O_MU_V = 1105408, O_VAR_V = 1625600, O_MASK = 2145792;
    int rm = blockIdx.x;                    // b*127+m, 4064 rows
    const float* hrow = hout + (size_t)rm * 529;
    int t = threadIdx.x;
    if (t < 128) {
        out[O_MU_M  + (size_t)rm * 128 + t] = hrow[9 + t];
        out[O_VAR_M + (size_t)rm * 128 + t] = expf(hrow[137 + t]);
        out[O_MU_V  + (size_t)rm * 128 + t] = hrow[273 + t];
        out[O_VAR_V + (size_t)rm * 128 + t] = expf(hrow[401 + t]);
    } else if (t == 128) {
        out[O_MASK + rm] = hrow[0];
    } else if (t == 129 || t == 130) {
        int boff = (t == 129) ? 1 : 265;
        size_t oo = ((t == 129) ? O_PI_M : O_PI_V) + (size_t)rm * 8;
        float v[8], mx = -1e30f;
#pragma unroll
        for (int j = 0; j < 8; ++j) { v[j] = hrow[boff + j]; mx = fmaxf(mx, v[j]); }
        float sm = 0.f;
#pragma unroll
        for (int j = 0; j < 8; ++j) { v[j] = expf(v[j] - mx); sm += v[j]; }
        float inv = 1.f / sm;
#pragma unroll
        for (int j = 0; j < 8; ++j) out[oo + j] = v[j] * inv;
    }
}

// ---------------- launcher ----------------
extern "C" void kernel_launch(void* const* d_in, const int* in_sizes, int n_in,
                              void* d_out, int out_size, void* d_ws, size_t ws_size,
                              hipStream_t stream) {
    (void)in_sizes; (void)n_in; (void)out_size; (void)ws_size;
    const float* input   = (const float*)d_in[0];
    const float* targets = (const float*)d_in[1];
    const float* W_emb   = (const float*)d_in[2];
    const float* b_emb   = (const float*)d_in[3];
    const float* sos     = (const float*)d_in[4];
    const float* Wqkv    = (const float*)d_in[5];
    const float* bqkv    = (const float*)d_in[6];
    const float* Wo      = (const float*)d_in[7];
    const float* bo      = (const float*)d_in[8];
    const float* W1      = (const float*)d_in[9];
    const float* b1      = (const float*)d_in[10];
    const float* W2      = (const float*)d_in[11];
    const float* b2      = (const float*)d_in[12];
    const float* g1      = (const float*)d_in[13];
    const float* be1     = (const float*)d_in[14];
    const float* g2      = (const float*)d_in[15];
    const float* be2     = (const float*)d_in[16];
    const float* Wm      = (const float*)d_in[17];
    const float* bm      = (const float*)d_in[18];
    const float* Wpi_m   = (const float*)d_in[19];
    const float* bpi_m   = (const float*)d_in[20];
    const float* Wmu_m   = (const float*)d_in[21];
    const float* bmu_m   = (const float*)d_in[22];
    const float* Wsg_m   = (const float*)d_in[23];
    const float* bsg_m   = (const float*)d_in[24];
    const float* Wpi_v   = (const float*)d_in[25];
    const float* bpi_v   = (const float*)d_in[26];
    const float* Wmu_v   = (const float*)d_in[27];
    const float* bmu_v   = (const float*)d_in[28];
    const float* Wsg_v   = (const float*)d_in[29];
    const float* bsg_v   = (const float*)d_in[30];
    float* out = (float*)d_out;

    char* ws = (char*)d_ws;                            // ~167 MB total
    float* pe      = (float*)(ws + 0);                 // 0.5 MB
    bf16*  xin     = (bf16*)(ws + 524288);             // 4.72 MB
    bf16*  wemb    = (bf16*)(ws + 5242880);            // 1.18 MB
    bf16*  whead   = (bf16*)(ws + 6422528);            // 1.31 MB (640 rows)
    float* bhead   = (float*)(ws + 7733248);           // 2.5 KB
    bf16*  xb      = (bf16*)(ws + 24513024);           // 8.4 MB (bf16 residual stream + GEMM input)
    bf16*  qkvb    = (bf16*)(ws + 32901632);           // 25.2 MB
    bf16*  ob      = (bf16*)(ws + 58067456);           // 8.4 MB (attn out, reused as FF hidden)
    bf16*  tmpb    = (bf16*)(ws + 66456064);           // 8.4 MB (gemm-out bf16, pre-LN)
    bf16*  wqb_all = (bf16*)(ws + 83233280);           // 37.7 MB (6 layers)
    bf16*  wob_all = (bf16*)(ws + 120982016);          // 12.6 MB
    bf16*  w1b_all = (bf16*)(ws + 133564928);          // 12.6 MB
    bf16*  w2b_all = (bf16*)(ws + 146147840);          // 12.6 MB
    float* hout    = (float*)(ws + 158730752);         // 8.6 MB

    prep_cvt_kernel<<<6497, 256, 0, stream>>>(input, targets, sos, W_emb,
                                              Wm, Wpi_m, Wmu_m, Wsg_m, Wpi_v, Wmu_v, Wsg_v,
                                              bm, bpi_m, bmu_m, bsg_m, bpi_v, bmu_v, bsg_v,
                                              Wqkv, Wo, W1, W2,
                                              pe, xin, wemb, whead, bhead,
                                              wqb_all, wob_all, w1b_all, w2b_all);
    // x = XIN @ Wemb^T + b + pe -> xb (bf16 residual stream); K=576 -> BK64 CFG=1
    gemm_bt<4, 1><<<dim3(8, 32, 1), 512, 0, stream>>>(xin, wemb, nullptr, xb, b_emb, pe,
                                                      4096, 1024, 576, 576, 576, 1024, 0, 0);
    for (int l = 0; l < 6; ++l) {
        const bf16* wqb = wqb_all + (size_t)l * 3145728;
        const bf16* wob = wob_all + (size_t)l * 1048576;
        const bf16* w1b = w1b_all + (size_t)l * 1048576;
        const bf16* w2b = w2b_all + (size_t)l * 1048576;
        // qkv = x @ Wqkv^T + b  (bf16 out) -- 768 blocks, single-buffer, 4 blocks/CU
        gemm_bt<0, 0><<<dim3(24, 32, 1), 256, 0, stream>>>(xb, wqb, nullptr, qkvb, bqkv + l * 3072,
                                                           nullptr, 4096, 3072, 1024, 1024, 1024, 3072, 0, 0);
        attn_fused<<<512, 256, 0, stream>>>(qkvb, ob);
        // go = o @ Wo^T + bo (bf16); residual folded into ln_res -- BK128 counted pipeline
        gemm_bt<0, 2><<<dim3(8, 32, 1), 512, 0, stream>>>(ob, wob, nullptr, tmpb, bo + l * 1024,
                                                          nullptr, 4096, 1024, 1024, 1024, 1024, 1024, 0, 0);
        ln_res_kernel<<<2048, 256, 0, stream>>>(tmpb, xb, g1 + l * 1024, be1 + l * 1024, xb);
        // t1 = relu(x @ W1^T + b1) (bf16, reuse ob)
        gemm_bt<1, 2><<<dim3(8, 32, 1), 512, 0, stream>>>(xb, w1b, nullptr, ob, b1 + l * 1024,
                                                          nullptr, 4096, 1024, 1024, 1024, 1024, 1024, 0, 0);
        // go = t1 @ W2^T + b2 (bf16); residual folded into ln_res
        gemm_bt<0, 2><<<dim3(8, 32, 1), 512, 0, stream>>>(ob, w2b, nullptr, tmpb, b2 + l * 1024,
                                                          nullptr, 4096, 1024, 1024, 1024, 1024, 1024, 0, 0);
        ln_res_kernel<<<2048, 256, 0, stream>>>(tmpb, xb, g2 + l * 1024, be2 + l * 1024, xb);
    }
    // heads: per-batch M=127 rows of x -> hout (B,127,529) -- grid 5/z, swizzle auto-skipped
    gemm_bt<3, 2><<<dim3(5, 1, 32), 512, 0, stream>>>(xb, whead, hout, nullptr, bhead, nullptr,
                                                      127, 529, 1024, 1024, 1024, 529, 131072LL, 67183LL);
    finalize_kernel<<<4064, 256, 0, stream>>>(hout, out);
}

// Round 15
// 750.800 us; speedup vs baseline: 1.0527x; 1.0527x over previous
//
#include <hip/hip_runtime.h>
#include <hip/hip_bf16.h>

typedef __hip_bfloat16 bf16;
typedef __attribute__((ext_vector_type(8))) short bfrag8;   // 8 bf16 (4 VGPR) MFMA A/B frag
typedef __attribute__((ext_vector_type(4))) float facc4;    // MFMA C/D frag
typedef __attribute__((ext_vector_type(4))) unsigned short us4;
typedef __attribute__((ext_vector_type(8))) unsigned short us8;
typedef __attribute__((ext_vector_type(4))) float f32x4;    // true clang vector (for nontemporal)

#define AS1C const __attribute__((address_space(1))) void
#define AS3  __attribute__((address_space(3))) void

__device__ __forceinline__ void gload_lds16(const void* src, void* dst) {
    __builtin_amdgcn_global_load_lds((AS1C*)src, (AS3*)dst, 16, 0, 0);
}

__device__ __forceinline__ unsigned short f2bf(float f) {   // RNE, finite inputs
    unsigned u = __float_as_uint(f);
    unsigned r = u + 0x7FFFu + ((u >> 16) & 1u);
    return (unsigned short)(r >> 16);
}
__device__ __forceinline__ float bf2f(unsigned short u) {   // exact
    return __uint_as_float((unsigned)u << 16);
}

// ------- merged prep+cvt: weights first (heavy), DENSE vectorized tail -------
__global__ void prep_cvt_kernel(const float* __restrict__ input, const float* __restrict__ targets,
                                const float* __restrict__ sos, const float* __restrict__ W_emb,
                                const float* __restrict__ Wm, const float* __restrict__ Wpi_m,
                                const float* __restrict__ Wmu_m, const float* __restrict__ Wsg_m,
                                const float* __restrict__ Wpi_v, const float* __restrict__ Wmu_v,
                                const float* __restrict__ Wsg_v,
                                const float* __restrict__ bm, const float* __restrict__ bpi_m,
                                const float* __restrict__ bmu_m, const float* __restrict__ bsg_m,
                                const float* __restrict__ bpi_v, const float* __restrict__ bmu_v,
                                const float* __restrict__ bsg_v,
                                const float* __restrict__ Wqkv, const float* __restrict__ Wo,
                                const float* __restrict__ W1, const float* __restrict__ W2,
                                float* __restrict__ pe, bf16* __restrict__ xin,
                                bf16* __restrict__ wemb, bf16* __restrict__ whead,
                                float* __restrict__ bhead,
                                bf16* __restrict__ wqb, bf16* __restrict__ wob,
                                bf16* __restrict__ w1b, bf16* __restrict__ w2b) {
    int bid = blockIdx.x;
    int t = threadIdx.x;
    if (bid < 4608) {                                    // weight cvt (NT loads, NT 16B stores)
        int l = bid / 768;
        int s = bid - l * 768;
        const float* src; bf16* dst;
        if (s < 384)      { src = Wqkv + (size_t)l * 3145728; dst = wqb + (size_t)l * 3145728; }
        else if (s < 512) { src = Wo + (size_t)l * 1048576; dst = wob + (size_t)l * 1048576; s -= 384; }
        else if (s < 640) { src = W1 + (size_t)l * 1048576; dst = w1b + (size_t)l * 1048576; s -= 512; }
        else              { src = W2 + (size_t)l * 1048576; dst = w2b + (size_t)l * 1048576; s -= 640; }
        size_t pbase = (size_t)s * 1024 + t;
#pragma unroll
        for (int it = 0; it < 4; ++it) {
            size_t o = (pbase + it * 256) * 8;           // 8 floats per pair
            const f32x4* p = (const f32x4*)(src + o);
            f32x4 v1 = __builtin_nontemporal_load(p);
            f32x4 v2 = __builtin_nontemporal_load(p + 1);
            us8 w8;
            w8[0] = f2bf(v1.x); w8[1] = f2bf(v1.y); w8[2] = f2bf(v1.z); w8[3] = f2bf(v1.w);
            w8[4] = f2bf(v2.x); w8[5] = f2bf(v2.y); w8[6] = f2bf(v2.z); w8[7] = f2bf(v2.w);
            __builtin_nontemporal_store(w8, (us8*)(dst + o));
        }
    } else if (bid < 4736) {                             // pe [128][1024]
        int s = bid - 4608;
        float4 v;
#pragma unroll
        for (int j = 0; j < 4; ++j) {
            int c = t * 4 + j;
            int i = c >> 1;
            float div = expf(-9.210340371976184f * (float)(2 * i) * (1.f / 1024.f));
            float a = (float)s * div;
            v[j] = (c & 1) ? cosf(a) : sinf(a);
        }
        *(float4*)(pe + (size_t)s * 1024 + t * 4) = v;
    } else if (bid < 5888) {                             // xin: 294912 us8-chunks (4096 rows x 72)
        int chunk = (bid - 4736) * 256 + t;
        int row = chunk / 72;
        int cc = chunk - row * 72;
        int b = row >> 7, s = row & 127;
        us8 w8;
        if (cc < 64) {
            const float* p = input + (size_t)b * 512 + cc * 8;
            float4 v1 = *(const float4*)p;
            float4 v2 = *(const float4*)(p + 4);
            w8[0] = f2bf(v1.x); w8[1] = f2bf(v1.y); w8[2] = f2bf(v1.z); w8[3] = f2bf(v1.w);
            w8[4] = f2bf(v2.x); w8[5] = f2bf(v2.y); w8[6] = f2bf(v2.z); w8[7] = f2bf(v2.w);
        } else {
#pragma unroll
            for (int j = 0; j < 8; ++j) {
                int col = cc * 8 + j;
                float v = 0.f;
                if (col < 545) {
                    int jj = col - 512;
                    v = (s == 0) ? sos[jj] : targets[((size_t)b * 127 + (s - 1)) * 33 + jj];
                }
                w8[j] = f2bf(v);
            }
        }
        *(us8*)(xin + (size_t)row * 576 + cc * 8) = w8;
    } else if (bid < 6176) {                             // wemb: pad 545->576
        int chunk = (bid - 5888) * 256 + t;
        int row = chunk / 72;
        int cc = chunk - row * 72;
        us8 w8;
#pragma unroll
        for (int j = 0; j < 8; ++j) {
            int col = cc * 8 + j;
            w8[j] = f2bf(col < 545 ? W_emb[(size_t)row * 545 + col] : 0.f);
        }
        *(us8*)(wemb + (size_t)row * 576 + cc * 8) = w8;
    } else if (bid < 6496) {                             // whead: 640 rows x 128 chunks
        int chunk = (bid - 6176) * 256 + t;
        int r = chunk >> 7;
        int cc = chunk & 127;
        const float* wsrc = nullptr; int off = 0;
        if (r == 0)        { wsrc = Wm;    off = 0; }
        else if (r < 9)    { wsrc = Wpi_m; off = r - 1; }
        else if (r < 137)  { wsrc = Wmu_m; off = r - 9; }
        else if (r < 265)  { wsrc = Wsg_m; off = r - 137; }
        else if (r < 273)  { wsrc = Wpi_v; off = r - 265; }
        else if (r < 401)  { wsrc = Wmu_v; off = r - 273; }
        else if (r < 529)  { wsrc = Wsg_v; off = r - 401; }
        us8 w8;
        if (wsrc) {
            const float* p = wsrc + (size_t)off * 1024 + cc * 8;
            float4 v1 = *(const float4*)p;
            float4 v2 = *(const float4*)(p + 4);
            w8[0] = f2bf(v1.x); w8[1] = f2bf(v1.y); w8[2] = f2bf(v1.z); w8[3] = f2bf(v1.w);
            w8[4] = f2bf(v2.x); w8[5] = f2bf(v2.y); w8[6] = f2bf(v2.z); w8[7] = f2bf(v2.w);
        } else {
#pragma unroll
            for (int j = 0; j < 8; ++j) w8[j] = 0;
        }
        *(us8*)(whead + (size_t)r * 1024 + cc * 8) = w8;
    } else {                                             // bhead: 529 scalars
        if (t < 529) {
            const float* bsrc; int off;
            if (t == 0)       { bsrc = bm;    off = 0; }
            else if (t < 9)   { bsrc = bpi_m; off = t - 1; }
            else if (t < 137) { bsrc = bmu_m; off = t - 9; }
            else if (t < 265) { bsrc = bsg_m; off = t - 137; }
            else if (t < 273) { bsrc = bpi_v; off = t - 265; }
            else if (t < 401) { bsrc = bmu_v; off = t - 273; }
            else              { bsrc = bsg_v; off = t - 401; }
            bhead[t] = bsrc[off];
        }
    }
}

// ---------------- main GEMM: C[M,N] = A[M,K] @ B[N,K]^T (+epilogue) ----------------
// 128x128 tile. Operand-swapped MFMA (C^T frags -> vectorized epilogue).
// XCD-chunked blockIdx swizzle (T1, bijective; applied when nwg%8==0).
// CFG=0: 256t, BK=64, single-buffer, 4 blocks/CU -- big grids (QKV).
// CFG=1: 512t, BK=64, dbuf(__syncthreads) -- grid-limited, K%128!=0 (embed).
// CFG=2: 512t, BK=128, dbuf(__syncthreads), 128KB LDS -- grid-limited, K%128==0.
// [counted-vmcnt pipeline attempted twice (r6 with sched_barriers, r14 without):
//  BOTH regressed ~80us total. T4 is gated on the full 8-phase structure (m218);
//  grafting it onto a 2-phase loop loses to the compiler's own schedule. Do not retry.]
// EPI: 0 bias->bf16 | 1 bias+relu->bf16 | 3 bias->f32 scalar (odd ldc) | 4 bias+pe->bf16
template<int EPI, int CFG>
__global__ __launch_bounds__(CFG ? 512 : 256, CFG ? 2 : 4) void gemm_bt(
    const bf16* __restrict__ A, const bf16* __restrict__ Bw,
    float* __restrict__ Cf, bf16* __restrict__ Cb,
    const float* __restrict__ bias, const float* __restrict__ pe,
    int M, int N, int K, int lda, int ldb, int ldc, long long Az, long long Cz)
{
    constexpr int NT  = CFG ? 512 : 256;    // threads
    constexpr int NB  = CFG ? 2 : 1;        // LDS buffers
    constexpr int MI  = CFG ? 2 : 4;        // per-wave M fragments
    constexpr int BK  = (CFG == 2) ? 128 : 64;
    constexpr int RB  = BK * 2;             // row bytes in LDS
    constexpr int CPR = BK / 8;             // 16B chunks per row
    constexpr int NCH = (128 * CPR) / NT;   // staging chunks per thread per array
    constexpr int KS  = BK / 32;            // 32-wide k-slices per tile
    __shared__ __align__(16) bf16 sA[NB][128 * BK];
    __shared__ __align__(16) bf16 sB[NB][128 * BK];
    const int t = threadIdx.x;
    const int w = t >> 6, la = t & 63;
    const int wm = CFG ? (w >> 1) * 32 : (w >> 1) * 64;
    const int wn = (w & 1) * 64;
    // XCD-chunked swizzle (identity when nwg not divisible by 8, e.g. heads grid)
    int nwgxy = gridDim.x * gridDim.y;
    int flat = blockIdx.y * gridDim.x + blockIdx.x;
    if ((nwgxy & 7) == 0) {
        int cpx = nwgxy >> 3;
        flat = (flat & 7) * cpx + (flat >> 3);
    }
    const int m0 = (flat / gridDim.x) * 128, n0 = (flat % gridDim.x) * 128;
    const int z = blockIdx.z;
    A += (long long)z * Az;

    facc4 zero4 = {0.f, 0.f, 0.f, 0.f};
    facc4 acc[MI][4];
#pragma unroll
    for (int mi = 0; mi < MI; ++mi)
#pragma unroll
        for (int ni = 0; ni < 4; ++ni) acc[mi][ni] = zero4;

    auto stage = [&](int buf, int kt) {
#pragma unroll
        for (int i = 0; i < NCH; ++i) {
            int c = i * NT + t;
            int r = c / CPR;
            int cc = c - r * CPR;
            int bc = (cc * 16) ^ ((r & 7) << 4);        // pre-swizzled source byte col
            gload_lds16(A + (size_t)(m0 + r) * lda + kt + (bc >> 1),
                        (char*)sA[buf] + (size_t)c * 16);
            gload_lds16(Bw + (size_t)(n0 + r) * ldb + kt + (bc >> 1),
                        (char*)sB[buf] + (size_t)c * 16);
        }
    };
    auto compute = [&](int buf) {
#pragma unroll
        for (int ks = 0; ks < KS; ++ks) {
            bfrag8 af[MI], bfv[4];
            const int koffb = (ks * 32 + (la >> 4) * 8) * 2;
#pragma unroll
            for (int i = 0; i < MI; ++i) {
                int rowa = wm + i * 16 + (la & 15);
                af[i] = *(const bfrag8*)((const char*)sA[buf] + rowa * RB + (koffb ^ ((rowa & 7) << 4)));
            }
#pragma unroll
            for (int i = 0; i < 4; ++i) {
                int rowb = wn + i * 16 + (la & 15);
                bfv[i] = *(const bfrag8*)((const char*)sB[buf] + rowb * RB + (koffb ^ ((rowb & 7) << 4)));
            }
#pragma unroll
            for (int mi = 0; mi < MI; ++mi)
#pragma unroll
                for (int ni = 0; ni < 4; ++ni)     // swapped operands -> C^T fragment
                    acc[mi][ni] = __builtin_amdgcn_mfma_f32_16x16x32_bf16(bfv[ni], af[mi], acc[mi][ni], 0, 0, 0);
        }
    };

    const int nk = K / BK;
    if constexpr (CFG) {
        stage(0, 0);
        __syncthreads();
        int cur = 0;
        for (int kt = 0; kt < nk; ++kt) {
            if (kt + 1 < nk) stage(cur ^ 1, (kt + 1) * BK);
            compute(cur);
            __syncthreads();        // drains stage(k+1) vmcnt; frees cur
            cur ^= 1;
        }
    } else {
        for (int kt = 0; kt < nk; ++kt) {
            stage(0, kt * BK);
            __syncthreads();
            compute(0);
            __syncthreads();
        }
    }
    // epilogue: thread holds C[row][colb..colb+3]
#pragma unroll
    for (int mi = 0; mi < MI; ++mi) {
        int row = m0 + wm + mi * 16 + (la & 15);
#pragma unroll
        for (int ni = 0; ni < 4; ++ni) {
            int colb = n0 + wn + ni * 16 + (la >> 4) * 4;
            if constexpr (EPI == 3) {               // scalar path (odd ldc / edge guards)
                if (row >= M) continue;
#pragma unroll
                for (int j = 0; j < 4; ++j) {
                    int col = colb + j;
                    if (col < N)
                        Cf[(size_t)z * Cz + (size_t)row * ldc + col] = acc[mi][ni][j] + bias[col];
                }
            } else {
                float4 bv = *(const float4*)(bias + colb);
                facc4 v = acc[mi][ni];
                v[0] += bv.x; v[1] += bv.y; v[2] += bv.z; v[3] += bv.w;
                size_t cidx = (size_t)row * ldc + colb;
                if constexpr (EPI == 0) {
                    us4 o; o.x = f2bf(v[0]); o.y = f2bf(v[1]); o.z = f2bf(v[2]); o.w = f2bf(v[3]);
                    *(us4*)(Cb + cidx) = o;
                } else if constexpr (EPI == 1) {
                    us4 o;
                    o.x = f2bf(v[0] > 0.f ? v[0] : 0.f); o.y = f2bf(v[1] > 0.f ? v[1] : 0.f);
                    o.z = f2bf(v[2] > 0.f ? v[2] : 0.f); o.w = f2bf(v[3] > 0.f ? v[3] : 0.f);
                    *(us4*)(Cb + cidx) = o;
                } else {                            // EPI == 4: bias + pe -> bf16
                    float4 p = *(const float4*)(pe + (size_t)(row & 127) * 1024 + colb);
                    us4 o;
                    o.x = f2bf(v[0] + p.x); o.y = f2bf(v[1] + p.y);
                    o.z = f2bf(v[2] + p.z); o.w = f2bf(v[3] + p.w);
                    *(us4*)(Cb + cidx) = o;
                }
            }
        }
    }
}

// ---------------- fused attention: one block per (b,h) ----------------
// S=128, D=64. Q in registers; K, V^T in LDS. In-register one-pass causal softmax.
// setprio(1) around MFMA clusters (T5).
__global__ __launch_bounds__(256) void attn_fused(const bf16* __restrict__ qkv, bf16* __restrict__ obf)
{
    __shared__ __align__(16) char lds[65536];
    char* sK  = lds + 16384;    // [128] rows x 128B, swizzled (dead after QK^T -> red arrays)
    char* sS  = lds + 32768;    // [128] rows x 256B bf16 (P)
    char* sVT = lds;            // [64] rows x 256B (V transposed)
    float* redm = (float*)(lds + 16384);            // [2][128] row max per col-half
    float* reds = (float*)(lds + 16384 + 1024);     // [2][128] row exp-sum per col-half

    const int t = threadIdx.x, w = t >> 6, la = t & 63;
    const int b = blockIdx.x >> 4, h = blockIdx.x & 15;
    const size_t base = (size_t)b * 128 * 3072 + (size_t)h * 64;

    const int wm = (w >> 1) * 64, wn = (w & 1) * 64;

    // phase 1: stage K into LDS; load Q fragments straight to registers
#pragma unroll
    for (int i = 0; i < 4; ++i) {
        int c = i * 256 + w * 64 + la;
        int r = c >> 3;
        int bc = ((c & 7) * 16) ^ ((r & 7) << 4);
        gload_lds16(qkv + base + 1024 + (size_t)r * 3072 + (bc >> 1),
                    sK + (size_t)(i * 256 + w * 64) * 16);
    }
    bfrag8 qf[4][2];
#pragma unroll
    for (int mi = 0; mi < 4; ++mi)
#pragma unroll
        for (int ks = 0; ks < 2; ++ks) {
            int rowa = wm + mi * 16 + (la & 15);
            int k0 = ks * 32 + (la >> 4) * 8;
            qf[mi][ks] = *(const bfrag8*)(qkv + base + (size_t)rowa * 3072 + k0);
        }
    __syncthreads();

    // phase 2: S = Q K^T (swapped mfma -> thread holds S[q][kb..kb+3], fp32)
    facc4 zero4 = {0.f, 0.f, 0.f, 0.f};
    facc4 acc[4][4];
#pragma unroll
    for (int mi = 0; mi < 4; ++mi)
#pragma unroll
        for (int ni = 0; ni < 4; ++ni) acc[mi][ni] = zero4;
    __builtin_amdgcn_s_setprio(1);
#pragma unroll
    for (int ks = 0; ks < 2; ++ks) {
        bfrag8 bfv[4];
        const int koffb = (ks * 32 + (la >> 4) * 8) * 2;
#pragma unroll
        for (int i = 0; i < 4; ++i) {
            int rowb = wn + i * 16 + (la & 15);
            bfv[i] = *(const bfrag8*)(sK + rowb * 128 + (koffb ^ ((rowb & 7) << 4)));
        }
#pragma unroll
        for (int mi = 0; mi < 4; ++mi)
#pragma unroll
            for (int ni = 0; ni < 4; ++ni)
                acc[mi][ni] = __builtin_amdgcn_mfma_f32_16x16x32_bf16(bfv[ni], qf[mi][ks], acc[mi][ni], 0, 0, 0);
    }
    __builtin_amdgcn_s_setprio(0);
    __syncthreads();        // all waves done reading sK

    // phase 3a: stage V transposed into sVT (overlaps softmax VALU below)
#pragma unroll
    for (int i = 0; i < 4; ++i) {
        int c = i * 256 + t;
        int r = c >> 3;             // key index s'
        int d0 = (c & 7) * 8;
        bfrag8 vv = *(const bfrag8*)(qkv + base + 2048 + (size_t)r * 3072 + d0);
#pragma unroll
        for (int j = 0; j < 8; ++j) {
            int d = d0 + j;
            *(short*)(sVT + d * 256 + ((2 * r) ^ ((d & 7) << 4))) = vv[j];
        }
    }

    // phase 3b: in-register causal softmax (one sweep per half)
    const int colh = (w & 1) * 128;
    float tmpm[4], tmps[4];
#pragma unroll
    for (int mi = 0; mi < 4; ++mi) {
        int q = wm + mi * 16 + (la & 15);
        float mx = -1e30f;
#pragma unroll
        for (int ni = 0; ni < 4; ++ni) {
            int kb = wn + ni * 16 + (la >> 4) * 4;
#pragma unroll
            for (int j = 0; j < 4; ++j) {
                float s = acc[mi][ni][j] * 0.125f;
                acc[mi][ni][j] = s;
                if (kb + j <= q) mx = fmaxf(mx, s);
            }
        }
        mx = fmaxf(mx, __shfl_xor(mx, 16));     // reduce over la>>4 (the k-axis lanes)
        mx = fmaxf(mx, __shfl_xor(mx, 32));
        float sm = 0.f;
#pragma unroll
        for (int ni = 0; ni < 4; ++ni) {
            int kb = wn + ni * 16 + (la >> 4) * 4;
#pragma unroll
            for (int j = 0; j < 4; ++j) {
                float e = (kb + j <= q) ? __expf(acc[mi][ni][j] - mx) : 0.f;
                acc[mi][ni][j] = e;
                sm += e;
            }
        }
        sm += __shfl_xor(sm, 16);
        sm += __shfl_xor(sm, 32);
        tmpm[mi] = mx; tmps[mi] = sm;
    }
    if ((la >> 4) == 0) {
#pragma unroll
        for (int mi = 0; mi < 4; ++mi) {
            redm[colh + wm + mi * 16 + la] = tmpm[mi];
            reds[colh + wm + mi * 16 + la] = tmps[mi];
        }
    }
    __syncthreads();
#pragma unroll
    for (int mi = 0; mi < 4; ++mi) {            // combine halves, normalize, pack P -> sS
        int q = wm + mi * 16 + (la & 15);
        float m0 = redm[q], m1 = redm[128 + q];
        float M = fmaxf(m0, m1);
        float tot = reds[q] * __expf(m0 - M) + reds[128 + q] * __expf(m1 - M);
        float sc = __expf(tmpm[mi] - M) / tot;
#pragma unroll
        for (int ni = 0; ni < 4; ++ni) {
            int kb = wn + ni * 16 + (la >> 4) * 4;
            us4 sv;
            sv.x = f2bf(acc[mi][ni][0] * sc); sv.y = f2bf(acc[mi][ni][1] * sc);
            sv.z = f2bf(acc[mi][ni][2] * sc); sv.w = f2bf(acc[mi][ni][3] * sc);
            *(us4*)(sS + q * 256 + ((2 * kb) ^ ((q & 7) << 4))) = sv;
        }
    }
    __syncthreads();                             // sS + sVT complete before PV

    // phase 4: O = P V  (wave tile 64M x 32N, K=128; swapped mfma -> packed O stores)
    const int wm2 = (w >> 1) * 64, wn2 = (w & 1) * 32;
    facc4 a2[4][2];
#pragma unroll
    for (int mi = 0; mi < 4; ++mi) { a2[mi][0] = zero4; a2[mi][1] = zero4; }
    __builtin_amdgcn_s_setprio(1);
#pragma unroll
    for (int ks = 0; ks < 4; ++ks) {
        bfrag8 pa[4], vb[2];
        const int koffb = (ks * 32 + (la >> 4) * 8) * 2;
#pragma unroll
        for (int mi = 0; mi < 4; ++mi) {
            int rowa = wm2 + mi * 16 + (la & 15);
            pa[mi] = *(const bfrag8*)(sS + rowa * 256 + (koffb ^ ((rowa & 7) << 4)));
        }
#pragma unroll
        for (int ni = 0; ni < 2; ++ni) {
            int rowb = wn2 + ni * 16 + (la & 15);
            vb[ni] = *(const bfrag8*)(sVT + rowb * 256 + (koffb ^ ((rowb & 7) << 4)));
        }
#pragma unroll
        for (int mi = 0; mi < 4; ++mi)
#pragma unroll
            for (int ni = 0; ni < 2; ++ni)
                a2[mi][ni] = __builtin_amdgcn_mfma_f32_16x16x32_bf16(vb[ni], pa[mi], a2[mi][ni], 0, 0, 0);
    }
    __builtin_amdgcn_s_setprio(0);
#pragma unroll
    for (int mi = 0; mi < 4; ++mi) {
        int s = wm2 + mi * 16 + (la & 15);
#pragma unroll
        for (int ni = 0; ni < 2; ++ni) {
            int db = wn2 + ni * 16 + (la >> 4) * 4;
            us4 ov;
            ov.x = f2bf(a2[mi][ni][0]); ov.y = f2bf(a2[mi][ni][1]);
            ov.z = f2bf(a2[mi][ni][2]); ov.w = f2bf(a2[mi][ni][3]);
            *(us4*)(obf + ((size_t)(b * 128 + s)) * 1024 + h * 64 + db) = ov;
        }
    }
}

// ------- fused residual + LayerNorm, all-bf16 stream: t = res + go; LN(t) -> xb -------
// 2 rows per block, 16B us8 I/O. In-place res==xb_out safe (element-owned).
__global__ __launch_bounds__(256) void ln_res_kernel(const bf16* __restrict__ go,
                                                     const bf16* __restrict__ res,
                                                     const float* __restrict__ g, const float* __restrict__ be,
                                                     bf16* __restrict__ xb_out)
{
    const int t = threadIdx.x;
    const int row = blockIdx.x * 2 + (t >> 7);   // 2 rows/block, 128 threads (2 waves) each
    const int ct = t & 127;
    size_t o = (size_t)row * 1024 + ct * 8;
    us8 gv8 = *(const us8*)(go + o);
    us8 rv8 = *(const us8*)(res + o);
    float v[8];
    float s = 0.f, q = 0.f;
#pragma unroll
    for (int j = 0; j < 8; ++j) {
        v[j] = bf2f(rv8[j]) + bf2f(gv8[j]);
        s += v[j];
        q += v[j] * v[j];
    }
#pragma unroll
    for (int off = 32; off; off >>= 1) {
        s += __shfl_xor(s, off);
        q += __shfl_xor(q, off);
    }
    __shared__ float ssum[4], sqs[4];
    if ((t & 63) == 0) { ssum[t >> 6] = s; sqs[t >> 6] = q; }
    __syncthreads();
    int rb = (t >> 7) * 2;
    s = ssum[rb] + ssum[rb + 1];
    q = sqs[rb] + sqs[rb + 1];
    float mean = s * (1.f / 1024.f);
    float var = q * (1.f / 1024.f) - mean * mean;
    float rstd = rsqrtf(var + 1e-5f);
    float4 g1v = *(const float4*)(g + ct * 8);
    float4 g2v = *(const float4*)(g + ct * 8 + 4);
    float4 b1v = *(const float4*)(be + ct * 8);
    float4 b2v = *(const float4*)(be + ct * 8 + 4);
    float ga[8] = {g1v.x, g1v.y, g1v.z, g1v.w, g2v.x, g2v.y, g2v.z, g2v.w};
    float ba[8] = {b1v.x, b1v.y, b1v.z, b1v.w, b2v.x, b2v.y, b2v.z, b2v.w};
    us8 ob;
#pragma unroll
    for (int j = 0; j < 8; ++j)
        ob[j] = f2bf((v[j] - mean) * rstd * ga[j] + ba[j]);
    *(us8*)(xb_out + o) = ob;
}

// ---------------- MDN finalize / scatter ----------------
__global__ void finalize_kernel(const float* __restrict__ hout, float* __restrict__ out) {
    const size_t O_PI_M = 0, O_MU_M = 32512, O_VAR_M = 552704, O_PI_V = 1072896,
                 O_MU_V = 1105408, O_VAR_V = 1625600, O_MASK = 2145792;
    int rm = blockIdx.x;                    // b*127+m, 4064 rows
    const float* hrow = hout + (size_t)rm * 529;
    int t = threadIdx.x;
    if (t < 128) {
        out[O_MU_M  + (size_t)rm * 128 + t] = hrow[9 + t];
        out[O_VAR_M + (size_t)rm * 128 + t] = expf(hrow[137 + t]);
        out[O_MU_V  + (size_t)rm * 128 + t] = hrow[273 + t];
        out[O_VAR_V + (size_t)rm * 128 + t] = expf(hrow[401 + t]);
    } else if (t == 128) {
        out[O_MASK + rm] = hrow[0];
    } else if (t == 129 || t == 130) {
        int boff = (t == 129) ? 1 : 265;
        size_t oo = ((t == 129) ? O_PI_M : O_PI_V) + (size_t)rm * 8;
        float v[8], mx = -1e30f;
#pragma unroll
        for (int j = 0; j < 8; ++j) { v[j] = hrow[boff + j]; mx = fmaxf(mx, v[j]); }
        float sm = 0.f;
#pragma unroll
        for (int j = 0; j < 8; ++j) { v[j] = expf(v[j] - mx); sm += v[j]; }
        float inv = 1.f / sm;
#pragma unroll
        for (int j = 0; j < 8; ++j) out[oo + j] = v[j] * inv;
    }
}

// ---------------- launcher ----------------
extern "C" void kernel_launch(void* const* d_in, const int* in_sizes, int n_in,
                              void* d_out, int out_size, void* d_ws, size_t ws_size,
                              hipStream_t stream) {
    (void)in_sizes; (void)n_in; (void)out_size; (void)ws_size;
    const float* input   = (const float*)d_in[0];
    const float* targets = (const float*)d_in[1];
    const float* W_emb   = (const float*)d_in[2];
    const float* b_emb   = (const float*)d_in[3];
    const float* sos     = (const float*)d_in[4];
    const float* Wqkv    = (const float*)d_in[5];
    const float* bqkv    = (const float*)d_in[6];
    const float* Wo      = (const float*)d_in[7];
    const float* bo      = (const float*)d_in[8];
    const float* W1      = (const float*)d_in[9];
    const float* b1      = (const float*)d_in[10];
    const float* W2      = (const float*)d_in[11];
    const float* b2      = (const float*)d_in[12];
    const float* g1      = (const float*)d_in[13];
    const float* be1     = (const float*)d_in[14];
    const float* g2      = (const float*)d_in[15];
    const float* be2     = (const float*)d_in[16];
    const float* Wm      = (const float*)d_in[17];
    const float* bm      = (const float*)d_in[18];
    const float* Wpi_m   = (const float*)d_in[19];
    const float* bpi_m   = (const float*)d_in[20];
    const float* Wmu_m   = (const float*)d_in[21];
    const float* bmu_m   = (const float*)d_in[22];
    const float* Wsg_m   = (const float*)d_in[23];
    const float* bsg_m   = (const float*)d_in[24];
    const float* Wpi_v   = (const float*)d_in[25];
    const float* bpi_v   = (const float*)d_in[26];
    const float* Wmu_v   = (const float*)d_in[27];
    const float* bmu_v   = (const float*)d_in[28];
    const float* Wsg_v   = (const float*)d_in[29];
    const float* bsg_v   = (const float*)d_in[30];
    float* out = (float*)d_out;

    char* ws = (char*)d_ws;                            // ~167 MB total
    float* pe      = (float*)(ws + 0);                 // 0.5 MB
    bf16*  xin     = (bf16*)(ws + 524288);             // 4.72 MB
    bf16*  wemb    = (bf16*)(ws + 5242880);            // 1.18 MB
    bf16*  whead   = (bf16*)(ws + 6422528);            // 1.31 MB (640 rows)
    float* bhead   = (float*)(ws + 7733248);           // 2.5 KB
    bf16*  xb      = (bf16*)(ws + 24513024);           // 8.4 MB (bf16 residual stream + GEMM input)
    bf16*  qkvb    = (bf16*)(ws + 32901632);           // 25.2 MB
    bf16*  ob      = (bf16*)(ws + 58067456);           // 8.4 MB (attn out, reused as FF hidden)
    bf16*  tmpb    = (bf16*)(ws + 66456064);           // 8.4 MB (gemm-out bf16, pre-LN)
    bf16*  wqb_all = (bf16*)(ws + 83233280);           // 37.7 MB (6 layers)
    bf16*  wob_all = (bf16*)(ws + 120982016);          // 12.6 MB
    bf16*  w1b_all = (bf16*)(ws + 133564928);          // 12.6 MB
    bf16*  w2b_all = (bf16*)(ws + 146147840);          // 12.6 MB
    float* hout    = (float*)(ws + 158730752);         // 8.6 MB

    prep_cvt_kernel<<<6497, 256, 0, stream>>>(input, targets, sos, W_emb,
                                              Wm, Wpi_m, Wmu_m, Wsg_m, Wpi_v, Wmu_v, Wsg_v,
                                              bm, bpi_m, bmu_m, bsg_m, bpi_v, bmu_v, bsg_v,
                                              Wqkv, Wo, W1, W2,
                                              pe, xin, wemb, whead, bhead,
                                              wqb_all, wob_all, w1b_all, w2b_all);
    // x = XIN @ Wemb^T + b + pe -> xb (bf16 residual stream); K=576 -> BK64 CFG=1
    gemm_bt<4, 1><<<dim3(8, 32, 1), 512, 0, stream>>>(xin, wemb, nullptr, xb, b_emb, pe,
                                                      4096, 1024, 576, 576, 576, 1024, 0, 0);
    for (int l = 0; l < 6; ++l) {
        const bf16* wqb = wqb_all + (size_t)l * 3145728;
        const bf16* wob = wob_all + (size_t)l * 1048576;
        const bf16* w1b = w1b_all + (size_t)l * 1048576;
        const bf16* w2b = w2b_all + (size_t)l * 1048576;
        // qkv = x @ Wqkv^T + b  (bf16 out) -- 768 blocks, single-buffer, 4 blocks/CU
        gemm_bt<0, 0><<<dim3(24, 32, 1), 256, 0, stream>>>(xb, wqb, nullptr, qkvb, bqkv + l * 3072,
                                                           nullptr, 4096, 3072, 1024, 1024, 1024, 3072, 0, 0);
        attn_fused<<<512, 256, 0, stream>>>(qkvb, ob);
        // go = o @ Wo^T + bo (bf16); residual folded into ln_res -- BK128 dbuf
        gemm_bt<0, 2><<<dim3(8, 32, 1), 512, 0, stream>>>(ob, wob, nullptr, tmpb, bo + l * 1024,
                                                          nullptr, 4096, 1024, 1024, 1024, 1024, 1024, 0, 0);
        ln_res_kernel<<<2048, 256, 0, stream>>>(tmpb, xb, g1 + l * 1024, be1 + l * 1024, xb);
        // t1 = relu(x @ W1^T + b1) (bf16, reuse ob)
        gemm_bt<1, 2><<<dim3(8, 32, 1), 512, 0, stream>>>(xb, w1b, nullptr, ob, b1 + l * 1024,
                                                          nullptr, 4096, 1024, 1024, 1024, 1024, 1024, 0, 0);
        // go = t1 @ W2^T + b2 (bf16); residual folded into ln_res
        gemm_bt<0, 2><<<dim3(8, 32, 1), 512, 0, stream>>>(ob, w2b, nullptr, tmpb, b2 + l * 1024,
                                                          nullptr, 4096, 1024, 1024, 1024, 1024, 1024, 0, 0);
        ln_res_kernel<<<2048, 256, 0, stream>>>(tmpb, xb, g2 + l * 1024, be2 + l * 1024, xb);
    }
    // heads: per-batch M=127 rows of x -> hout (B,127,529) -- grid 5/z, swizzle auto-skipped
    gemm_bt<3, 2><<<dim3(5, 1, 32), 512, 0, stream>>>(xb, whead, hout, nullptr, bhead, nullptr,
                                                      127, 529, 1024, 1024, 1024, 529, 131072LL, 67183LL);
    finalize_kernel<<<4064, 256, 0, stream>>>(hout, out);
}

// Round 16
// 708.911 us; speedup vs baseline: 1.1149x; 1.0591x over previous
//
#include <hip/hip_runtime.h>
#include <hip/hip_bf16.h>

typedef __hip_bfloat16 bf16;
typedef __attribute__((ext_vector_type(8))) short bfrag8;   // 8 bf16 (4 VGPR) MFMA A/B frag
typedef __attribute__((ext_vector_type(4))) float facc4;    // MFMA C/D frag
typedef __attribute__((ext_vector_type(4))) unsigned short us4;
typedef __attribute__((ext_vector_type(8))) unsigned short us8;
typedef __attribute__((ext_vector_type(4))) float f32x4;    // true clang vector (for nontemporal)

#define AS1C const __attribute__((address_space(1))) void
#define AS3  __attribute__((address_space(3))) void

__device__ __forceinline__ void gload_lds16(const void* src, void* dst) {
    __builtin_amdgcn_global_load_lds((AS1C*)src, (AS3*)dst, 16, 0, 0);
}

__device__ __forceinline__ unsigned short f2bf(float f) {   // RNE, finite inputs
    unsigned u = __float_as_uint(f);
    unsigned r = u + 0x7FFFu + ((u >> 16) & 1u);
    return (unsigned short)(r >> 16);
}
__device__ __forceinline__ float bf2f(unsigned short u) {   // exact
    return __uint_as_float((unsigned)u << 16);
}

// ------- merged prep+cvt: weights first (heavy), DENSE vectorized tail -------
// NT loads on the fp32 source (read-once); CACHED stores on the bf16 output --
// round-14/15 A/B showed NT output stores cost ~40us: the GEMMs re-read these
// 74MB from L3, which NT bypasses.
__global__ void prep_cvt_kernel(const float* __restrict__ input, const float* __restrict__ targets,
                                const float* __restrict__ sos, const float* __restrict__ W_emb,
                                const float* __restrict__ Wm, const float* __restrict__ Wpi_m,
                                const float* __restrict__ Wmu_m, const float* __restrict__ Wsg_m,
                                const float* __restrict__ Wpi_v, const float* __restrict__ Wmu_v,
                                const float* __restrict__ Wsg_v,
                                const float* __restrict__ bm, const float* __restrict__ bpi_m,
                                const float* __restrict__ bmu_m, const float* __restrict__ bsg_m,
                                const float* __restrict__ bpi_v, const float* __restrict__ bmu_v,
                                const float* __restrict__ bsg_v,
                                const float* __restrict__ Wqkv, const float* __restrict__ Wo,
                                const float* __restrict__ W1, const float* __restrict__ W2,
                                float* __restrict__ pe, bf16* __restrict__ xin,
                                bf16* __restrict__ wemb, bf16* __restrict__ whead,
                                float* __restrict__ bhead,
                                bf16* __restrict__ wqb, bf16* __restrict__ wob,
                                bf16* __restrict__ w1b, bf16* __restrict__ w2b) {
    int bid = blockIdx.x;
    int t = threadIdx.x;
    if (bid < 4608) {                                    // weight cvt
        int l = bid / 768;
        int s = bid - l * 768;
        const float* src; bf16* dst;
        if (s < 384)      { src = Wqkv + (size_t)l * 3145728; dst = wqb + (size_t)l * 3145728; }
        else if (s < 512) { src = Wo + (size_t)l * 1048576; dst = wob + (size_t)l * 1048576; s -= 384; }
        else if (s < 640) { src = W1 + (size_t)l * 1048576; dst = w1b + (size_t)l * 1048576; s -= 512; }
        else              { src = W2 + (size_t)l * 1048576; dst = w2b + (size_t)l * 1048576; s -= 640; }
        size_t pbase = (size_t)s * 1024 + t;
#pragma unroll
        for (int it = 0; it < 4; ++it) {
            size_t o = (pbase + it * 256) * 8;           // 8 floats per pair
            const f32x4* p = (const f32x4*)(src + o);
            f32x4 v1 = __builtin_nontemporal_load(p);
            f32x4 v2 = __builtin_nontemporal_load(p + 1);
            us8 w8;
            w8[0] = f2bf(v1.x); w8[1] = f2bf(v1.y); w8[2] = f2bf(v1.z); w8[3] = f2bf(v1.w);
            w8[4] = f2bf(v2.x); w8[5] = f2bf(v2.y); w8[6] = f2bf(v2.z); w8[7] = f2bf(v2.w);
            *(us8*)(dst + o) = w8;                       // cached store (GEMMs re-read from L3)
        }
    } else if (bid < 4736) {                             // pe [128][1024]
        int s = bid - 4608;
        float4 v;
#pragma unroll
        for (int j = 0; j < 4; ++j) {
            int c = t * 4 + j;
            int i = c >> 1;
            float div = expf(-9.210340371976184f * (float)(2 * i) * (1.f / 1024.f));
            float a = (float)s * div;
            v[j] = (c & 1) ? cosf(a) : sinf(a);
        }
        *(float4*)(pe + (size_t)s * 1024 + t * 4) = v;
    } else if (bid < 5888) {                             // xin: 294912 us8-chunks (4096 rows x 72)
        int chunk = (bid - 4736) * 256 + t;
        int row = chunk / 72;
        int cc = chunk - row * 72;
        int b = row >> 7, s = row & 127;
        us8 w8;
        if (cc < 64) {
            const float* p = input + (size_t)b * 512 + cc * 8;
            float4 v1 = *(const float4*)p;
            float4 v2 = *(const float4*)(p + 4);
            w8[0] = f2bf(v1.x); w8[1] = f2bf(v1.y); w8[2] = f2bf(v1.z); w8[3] = f2bf(v1.w);
            w8[4] = f2bf(v2.x); w8[5] = f2bf(v2.y); w8[6] = f2bf(v2.z); w8[7] = f2bf(v2.w);
        } else {
#pragma unroll
            for (int j = 0; j < 8; ++j) {
                int col = cc * 8 + j;
                float v = 0.f;
                if (col < 545) {
                    int jj = col - 512;
                    v = (s == 0) ? sos[jj] : targets[((size_t)b * 127 + (s - 1)) * 33 + jj];
                }
                w8[j] = f2bf(v);
            }
        }
        *(us8*)(xin + (size_t)row * 576 + cc * 8) = w8;
    } else if (bid < 6176) {                             // wemb: pad 545->576
        int chunk = (bid - 5888) * 256 + t;
        int row = chunk / 72;
        int cc = chunk - row * 72;
        us8 w8;
#pragma unroll
        for (int j = 0; j < 8; ++j) {
            int col = cc * 8 + j;
            w8[j] = f2bf(col < 545 ? W_emb[(size_t)row * 545 + col] : 0.f);
        }
        *(us8*)(wemb + (size_t)row * 576 + cc * 8) = w8;
    } else if (bid < 6496) {                             // whead: 640 rows x 128 chunks
        int chunk = (bid - 6176) * 256 + t;
        int r = chunk >> 7;
        int cc = chunk & 127;
        const float* wsrc = nullptr; int off = 0;
        if (r == 0)        { wsrc = Wm;    off = 0; }
        else if (r < 9)    { wsrc = Wpi_m; off = r - 1; }
        else if (r < 137)  { wsrc = Wmu_m; off = r - 9; }
        else if (r < 265)  { wsrc = Wsg_m; off = r - 137; }
        else if (r < 273)  { wsrc = Wpi_v; off = r - 265; }
        else if (r < 401)  { wsrc = Wmu_v; off = r - 273; }
        else if (r < 529)  { wsrc = Wsg_v; off = r - 401; }
        us8 w8;
        if (wsrc) {
            const float* p = wsrc + (size_t)off * 1024 + cc * 8;
            float4 v1 = *(const float4*)p;
            float4 v2 = *(const float4*)(p + 4);
            w8[0] = f2bf(v1.x); w8[1] = f2bf(v1.y); w8[2] = f2bf(v1.z); w8[3] = f2bf(v1.w);
            w8[4] = f2bf(v2.x); w8[5] = f2bf(v2.y); w8[6] = f2bf(v2.z); w8[7] = f2bf(v2.w);
        } else {
#pragma unroll
            for (int j = 0; j < 8; ++j) w8[j] = 0;
        }
        *(us8*)(whead + (size_t)r * 1024 + cc * 8) = w8;
    } else {                                             // bhead: 529 scalars
        if (t < 529) {
            const float* bsrc; int off;
            if (t == 0)       { bsrc = bm;    off = 0; }
            else if (t < 9)   { bsrc = bpi_m; off = t - 1; }
            else if (t < 137) { bsrc = bmu_m; off = t - 9; }
            else if (t < 265) { bsrc = bsg_m; off = t - 137; }
            else if (t < 273) { bsrc = bpi_v; off = t - 265; }
            else if (t < 401) { bsrc = bmu_v; off = t - 273; }
            else              { bsrc = bsg_v; off = t - 401; }
            bhead[t] = bsrc[off];
        }
    }
}

// ---------------- main GEMM: C[M,N] = A[M,K] @ B[N,K]^T (+epilogue) ----------------
// 128x128 tile. Operand-swapped MFMA (C^T frags -> vectorized epilogue).
// XCD-chunked blockIdx swizzle (T1, bijective; applied when nwg%8==0).
// CFG=0: 256t, BK=64, single-buffer, 4 blocks/CU -- big grids (QKV).
// CFG=1: 512t, BK=64, dbuf(__syncthreads) -- grid-limited, K%128!=0 (embed).
// CFG=2: 512t, BK=128, dbuf(__syncthreads), 128KB LDS -- grid-limited, K%128==0.
// [counted-vmcnt pipeline attempted twice (r6, r14): both regressed ~40us. T4 is
//  gated on the full 8-phase structure (m218); do not retry on a 2-phase loop.]
// EPI: 0 bias->bf16 | 1 bias+relu->bf16 | 3 bias->f32 scalar (odd ldc) | 4 bias+pe->bf16
template<int EPI, int CFG>
__global__ __launch_bounds__(CFG ? 512 : 256, CFG ? 2 : 4) void gemm_bt(
    const bf16* __restrict__ A, const bf16* __restrict__ Bw,
    float* __restrict__ Cf, bf16* __restrict__ Cb,
    const float* __restrict__ bias, const float* __restrict__ pe,
    int M, int N, int K, int lda, int ldb, int ldc, long long Az, long long Cz)
{
    constexpr int NT  = CFG ? 512 : 256;    // threads
    constexpr int NB  = CFG ? 2 : 1;        // LDS buffers
    constexpr int MI  = CFG ? 2 : 4;        // per-wave M fragments
    constexpr int BK  = (CFG == 2) ? 128 : 64;
    constexpr int RB  = BK * 2;             // row bytes in LDS
    constexpr int CPR = BK / 8;             // 16B chunks per row
    constexpr int NCH = (128 * CPR) / NT;   // staging chunks per thread per array
    constexpr int KS  = BK / 32;            // 32-wide k-slices per tile
    __shared__ __align__(16) bf16 sA[NB][128 * BK];
    __shared__ __align__(16) bf16 sB[NB][128 * BK];
    const int t = threadIdx.x;
    const int w = t >> 6, la = t & 63;
    const int wm = CFG ? (w >> 1) * 32 : (w >> 1) * 64;
    const int wn = (w & 1) * 64;
    // XCD-chunked swizzle (identity when nwg not divisible by 8, e.g. heads grid)
    int nwgxy = gridDim.x * gridDim.y;
    int flat = blockIdx.y * gridDim.x + blockIdx.x;
    if ((nwgxy & 7) == 0) {
        int cpx = nwgxy >> 3;
        flat = (flat & 7) * cpx + (flat >> 3);
    }
    const int m0 = (flat / gridDim.x) * 128, n0 = (flat % gridDim.x) * 128;
    const int z = blockIdx.z;
    A += (long long)z * Az;

    facc4 zero4 = {0.f, 0.f, 0.f, 0.f};
    facc4 acc[MI][4];
#pragma unroll
    for (int mi = 0; mi < MI; ++mi)
#pragma unroll
        for (int ni = 0; ni < 4; ++ni) acc[mi][ni] = zero4;

    auto stage = [&](int buf, int kt) {
#pragma unroll
        for (int i = 0; i < NCH; ++i) {
            int c = i * NT + t;
            int r = c / CPR;
            int cc = c - r * CPR;
            int bc = (cc * 16) ^ ((r & 7) << 4);        // pre-swizzled source byte col
            gload_lds16(A + (size_t)(m0 + r) * lda + kt + (bc >> 1),
                        (char*)sA[buf] + (size_t)c * 16);
            gload_lds16(Bw + (size_t)(n0 + r) * ldb + kt + (bc >> 1),
                        (char*)sB[buf] + (size_t)c * 16);
        }
    };
    auto compute = [&](int buf) {
#pragma unroll
        for (int ks = 0; ks < KS; ++ks) {
            bfrag8 af[MI], bfv[4];
            const int koffb = (ks * 32 + (la >> 4) * 8) * 2;
#pragma unroll
            for (int i = 0; i < MI; ++i) {
                int rowa = wm + i * 16 + (la & 15);
                af[i] = *(const bfrag8*)((const char*)sA[buf] + rowa * RB + (koffb ^ ((rowa & 7) << 4)));
            }
#pragma unroll
            for (int i = 0; i < 4; ++i) {
                int rowb = wn + i * 16 + (la & 15);
                bfv[i] = *(const bfrag8*)((const char*)sB[buf] + rowb * RB + (koffb ^ ((rowb & 7) << 4)));
            }
#pragma unroll
            for (int mi = 0; mi < MI; ++mi)
#pragma unroll
                for (int ni = 0; ni < 4; ++ni)     // swapped operands -> C^T fragment
                    acc[mi][ni] = __builtin_amdgcn_mfma_f32_16x16x32_bf16(bfv[ni], af[mi], acc[mi][ni], 0, 0, 0);
        }
    };

    const int nk = K / BK;
    if constexpr (CFG) {
        stage(0, 0);
        __syncthreads();
        int cur = 0;
        for (int kt = 0; kt < nk; ++kt) {
            if (kt + 1 < nk) stage(cur ^ 1, (kt + 1) * BK);
            compute(cur);
            __syncthreads();        // drains stage(k+1) vmcnt; frees cur
            cur ^= 1;
        }
    } else {
        for (int kt = 0; kt < nk; ++kt) {
            stage(0, kt * BK);
            __syncthreads();
            compute(0);
            __syncthreads();
        }
    }
    // epilogue: thread holds C[row][colb..colb+3]
#pragma unroll
    for (int mi = 0; mi < MI; ++mi) {
        int row = m0 + wm + mi * 16 + (la & 15);
#pragma unroll
        for (int ni = 0; ni < 4; ++ni) {
            int colb = n0 + wn + ni * 16 + (la >> 4) * 4;
            if constexpr (EPI == 3) {               // scalar path (odd ldc / edge guards)
                if (row >= M) continue;
#pragma unroll
                for (int j = 0; j < 4; ++j) {
                    int col = colb + j;
                    if (col < N)
                        Cf[(size_t)z * Cz + (size_t)row * ldc + col] = acc[mi][ni][j] + bias[col];
                }
            } else {
                float4 bv = *(const float4*)(bias + colb);
                facc4 v = acc[mi][ni];
                v[0] += bv.x; v[1] += bv.y; v[2] += bv.z; v[3] += bv.w;
                size_t cidx = (size_t)row * ldc + colb;
                if constexpr (EPI == 0) {
                    us4 o; o.x = f2bf(v[0]); o.y = f2bf(v[1]); o.z = f2bf(v[2]); o.w = f2bf(v[3]);
                    *(us4*)(Cb + cidx) = o;
                } else if constexpr (EPI == 1) {
                    us4 o;
                    o.x = f2bf(v[0] > 0.f ? v[0] : 0.f); o.y = f2bf(v[1] > 0.f ? v[1] : 0.f);
                    o.z = f2bf(v[2] > 0.f ? v[2] : 0.f); o.w = f2bf(v[3] > 0.f ? v[3] : 0.f);
                    *(us4*)(Cb + cidx) = o;
                } else {                            // EPI == 4: bias + pe -> bf16
                    float4 p = *(const float4*)(pe + (size_t)(row & 127) * 1024 + colb);
                    us4 o;
                    o.x = f2bf(v[0] + p.x); o.y = f2bf(v[1] + p.y);
                    o.z = f2bf(v[2] + p.z); o.w = f2bf(v[3] + p.w);
                    *(us4*)(Cb + cidx) = o;
                }
            }
        }
    }
}

// ---------------- fused attention: one block per (b,h) ----------------
// S=128, D=64. Q in registers; K, V^T in LDS. In-register one-pass causal softmax.
// setprio(1) around MFMA clusters (T5).
__global__ __launch_bounds__(256) void attn_fused(const bf16* __restrict__ qkv, bf16* __restrict__ obf)
{
    __shared__ __align__(16) char lds[65536];
    char* sK  = lds + 16384;    // [128] rows x 128B, swizzled (dead after QK^T -> red arrays)
    char* sS  = lds + 32768;    // [128] rows x 256B bf16 (P)
    char* sVT = lds;            // [64] rows x 256B (V transposed)
    float* redm = (float*)(lds + 16384);            // [2][128] row max per col-half
    float* reds = (float*)(lds + 16384 + 1024);     // [2][128] row exp-sum per col-half

    const int t = threadIdx.x, w = t >> 6, la = t & 63;
    const int b = blockIdx.x >> 4, h = blockIdx.x & 15;
    const size_t base = (size_t)b * 128 * 3072 + (size_t)h * 64;

    const int wm = (w >> 1) * 64, wn = (w & 1) * 64;

    // phase 1: stage K into LDS; load Q fragments straight to registers
#pragma unroll
    for (int i = 0; i < 4; ++i) {
        int c = i * 256 + w * 64 + la;
        int r = c >> 3;
        int bc = ((c & 7) * 16) ^ ((r & 7) << 4);
        gload_lds16(qkv + base + 1024 + (size_t)r * 3072 + (bc >> 1),
                    sK + (size_t)(i * 256 + w * 64) * 16);
    }
    bfrag8 qf[4][2];
#pragma unroll
    for (int mi = 0; mi < 4; ++mi)
#pragma unroll
        for (int ks = 0; ks < 2; ++ks) {
            int rowa = wm + mi * 16 + (la & 15);
            int k0 = ks * 32 + (la >> 4) * 8;
            qf[mi][ks] = *(const bfrag8*)(qkv + base + (size_t)rowa * 3072 + k0);
        }
    __syncthreads();

    // phase 2: S = Q K^T (swapped mfma -> thread holds S[q][kb..kb+3], fp32)
    facc4 zero4 = {0.f, 0.f, 0.f, 0.f};
    facc4 acc[4][4];
#pragma unroll
    for (int mi = 0; mi < 4; ++mi)
#pragma unroll
        for (int ni = 0; ni < 4; ++ni) acc[mi][ni] = zero4;
    __builtin_amdgcn_s_setprio(1);
#pragma unroll
    for (int ks = 0; ks < 2; ++ks) {
        bfrag8 bfv[4];
        const int koffb = (ks * 32 + (la >> 4) * 8) * 2;
#pragma unroll
        for (int i = 0; i < 4; ++i) {
            int rowb = wn + i * 16 + (la & 15);
            bfv[i] = *(const bfrag8*)(sK + rowb * 128 + (koffb ^ ((rowb & 7) << 4)));
        }
#pragma unroll
        for (int mi = 0; mi < 4; ++mi)
#pragma unroll
            for (int ni = 0; ni < 4; ++ni)
                acc[mi][ni] = __builtin_amdgcn_mfma_f32_16x16x32_bf16(bfv[ni], qf[mi][ks], acc[mi][ni], 0, 0, 0);
    }
    __builtin_amdgcn_s_setprio(0);
    __syncthreads();        // all waves done reading sK

    // phase 3a: stage V transposed into sVT (overlaps softmax VALU below)
#pragma unroll
    for (int i = 0; i < 4; ++i) {
        int c = i * 256 + t;
        int r = c >> 3;             // key index s'
        int d0 = (c & 7) * 8;
        bfrag8 vv = *(const bfrag8*)(qkv + base + 2048 + (size_t)r * 3072 + d0);
#pragma unroll
        for (int j = 0; j < 8; ++j) {
            int d = d0 + j;
            *(short*)(sVT + d * 256 + ((2 * r) ^ ((d & 7) << 4))) = vv[j];
        }
    }

    // phase 3b: in-register causal softmax (one sweep per half)
    const int colh = (w & 1) * 128;
    float tmpm[4], tmps[4];
#pragma unroll
    for (int mi = 0; mi < 4; ++mi) {
        int q = wm + mi * 16 + (la & 15);
        float mx = -1e30f;
#pragma unroll
        for (int ni = 0; ni < 4; ++ni) {
            int kb = wn + ni * 16 + (la >> 4) * 4;
#pragma unroll
            for (int j = 0; j < 4; ++j) {
                float s = acc[mi][ni][j] * 0.125f;
                acc[mi][ni][j] = s;
                if (kb + j <= q) mx = fmaxf(mx, s);
            }
        }
        mx = fmaxf(mx, __shfl_xor(mx, 16));     // reduce over la>>4 (the k-axis lanes)
        mx = fmaxf(mx, __shfl_xor(mx, 32));
        float sm = 0.f;
#pragma unroll
        for (int ni = 0; ni < 4; ++ni) {
            int kb = wn + ni * 16 + (la >> 4) * 4;
#pragma unroll
            for (int j = 0; j < 4; ++j) {
                float e = (kb + j <= q) ? __expf(acc[mi][ni][j] - mx) : 0.f;
                acc[mi][ni][j] = e;
                sm += e;
            }
        }
        sm += __shfl_xor(sm, 16);
        sm += __shfl_xor(sm, 32);
        tmpm[mi] = mx; tmps[mi] = sm;
    }
    if ((la >> 4) == 0) {
#pragma unroll
        for (int mi = 0; mi < 4; ++mi) {
            redm[colh + wm + mi * 16 + la] = tmpm[mi];
            reds[colh + wm + mi * 16 + la] = tmps[mi];
        }
    }
    __syncthreads();
#pragma unroll
    for (int mi = 0; mi < 4; ++mi) {            // combine halves, normalize, pack P -> sS
        int q = wm + mi * 16 + (la & 15);
        float m0 = redm[q], m1 = redm[128 + q];
        float M = fmaxf(m0, m1);
        float tot = reds[q] * __expf(m0 - M) + reds[128 + q] * __expf(m1 - M);
        float sc = __expf(tmpm[mi] - M) / tot;
#pragma unroll
        for (int ni = 0; ni < 4; ++ni) {
            int kb = wn + ni * 16 + (la >> 4) * 4;
            us4 sv;
            sv.x = f2bf(acc[mi][ni][0] * sc); sv.y = f2bf(acc[mi][ni][1] * sc);
            sv.z = f2bf(acc[mi][ni][2] * sc); sv.w = f2bf(acc[mi][ni][3] * sc);
            *(us4*)(sS + q * 256 + ((2 * kb) ^ ((q & 7) << 4))) = sv;
        }
    }
    __syncthreads();                             // sS + sVT complete before PV

    // phase 4: O = P V  (wave tile 64M x 32N, K=128; swapped mfma -> packed O stores)
    const int wm2 = (w >> 1) * 64, wn2 = (w & 1) * 32;
    facc4 a2[4][2];
#pragma unroll
    for (int mi = 0; mi < 4; ++mi) { a2[mi][0] = zero4; a2[mi][1] = zero4; }
    __builtin_amdgcn_s_setprio(1);
#pragma unroll
    for (int ks = 0; ks < 4; ++ks) {
        bfrag8 pa[4], vb[2];
        const int koffb = (ks * 32 + (la >> 4) * 8) * 2;
#pragma unroll
        for (int mi = 0; mi < 4; ++mi) {
            int rowa = wm2 + mi * 16 + (la & 15);
            pa[mi] = *(const bfrag8*)(sS + rowa * 256 + (koffb ^ ((rowa & 7) << 4)));
        }
#pragma unroll
        for (int ni = 0; ni < 2; ++ni) {
            int rowb = wn2 + ni * 16 + (la & 15);
            vb[ni] = *(const bfrag8*)(sVT + rowb * 256 + (koffb ^ ((rowb & 7) << 4)));
        }
#pragma unroll
        for (int mi = 0; mi < 4; ++mi)
#pragma unroll
            for (int ni = 0; ni < 2; ++ni)
                a2[mi][ni] = __builtin_amdgcn_mfma_f32_16x16x32_bf16(vb[ni], pa[mi], a2[mi][ni], 0, 0, 0);
    }
    __builtin_amdgcn_s_setprio(0);
#pragma unroll
    for (int mi = 0; mi < 4; ++mi) {
        int s = wm2 + mi * 16 + (la & 15);
#pragma unroll
        for (int ni = 0; ni < 2; ++ni) {
            int db = wn2 + ni * 16 + (la >> 4) * 4;
            us4 ov;
            ov.x = f2bf(a2[mi][ni][0]); ov.y = f2bf(a2[mi][ni][1]);
            ov.z = f2bf(a2[mi][ni][2]); ov.w = f2bf(a2[mi][ni][3]);
            *(us4*)(obf + ((size_t)(b * 128 + s)) * 1024 + h * 64 + db) = ov;
        }
    }
}

// ------- fused residual + LayerNorm, all-bf16 stream: t = res + go; LN(t) -> xb -------
// 2 rows per block, 16B us8 I/O. In-place res==xb_out safe (element-owned).
__global__ __launch_bounds__(256) void ln_res_kernel(const bf16* __restrict__ go,
                                                     const bf16* __restrict__ res,
                                                     const float* __restrict__ g, const float* __restrict__ be,
                                                     bf16* __restrict__ xb_out)
{
    const int t = threadIdx.x;
    const int row = blockIdx.x * 2 + (t >> 7);   // 2 rows/block, 128 threads (2 waves) each
    const int ct = t & 127;
    size_t o = (size_t)row * 1024 + ct * 8;
    us8 gv8 = *(const us8*)(go + o);
    us8 rv8 = *(const us8*)(res + o);
    float v[8];
    float s = 0.f, q = 0.f;
#pragma unroll
    for (int j = 0; j < 8; ++j) {
        v[j] = bf2f(rv8[j]) + bf2f(gv8[j]);
        s += v[j];
        q += v[j] * v[j];
    }
#pragma unroll
    for (int off = 32; off; off >>= 1) {
        s += __shfl_xor(s, off);
        q += __shfl_xor(q, off);
    }
    __shared__ float ssum[4], sqs[4];
    if ((t & 63) == 0) { ssum[t >> 6] = s; sqs[t >> 6] = q; }
    __syncthreads();
    int rb = (t >> 7) * 2;
    s = ssum[rb] + ssum[rb + 1];
    q = sqs[rb] + sqs[rb + 1];
    float mean = s * (1.f / 1024.f);
    float var = q * (1.f / 1024.f) - mean * mean;
    float rstd = rsqrtf(var + 1e-5f);
    float4 g1v = *(const float4*)(g + ct * 8);
    float4 g2v = *(const float4*)(g + ct * 8 + 4);
    float4 b1v = *(const float4*)(be + ct * 8);
    float4 b2v = *(const float4*)(be + ct * 8 + 4);
    float ga[8] = {g1v.x, g1v.y, g1v.z, g1v.w, g2v.x, g2v.y, g2v.z, g2v.w};
    float ba[8] = {b1v.x, b1v.y, b1v.z, b1v.w, b2v.x, b2v.y, b2v.z, b2v.w};
    us8 ob;
#pragma unroll
    for (int j = 0; j < 8; ++j)
        ob[j] = f2bf((v[j] - mean) * rstd * ga[j] + ba[j]);
    *(us8*)(xb_out + o) = ob;
}

// ---------------- MDN finalize / scatter ----------------
__global__ void finalize_kernel(const float* __restrict__ hout, float* __restrict__ out) {
    const size_t O_PI_M = 0, O_MU_M = 32512, O_VAR_M = 552704, O_PI_V = 1072896,
                 O_MU_V = 1105408, O_VAR_V = 1625600, O_MASK = 2145792;
    int rm = blockIdx.x;                    // b*127+m, 4064 rows
    const float* hrow = hout + (size_t)rm * 529;
    int t = threadIdx.x;
    if (t < 128) {
        out[O_MU_M  + (size_t)rm * 128 + t] = hrow[9 + t];
        out[O_VAR_M + (size_t)rm * 128 + t] = expf(hrow[137 + t]);
        out[O_MU_V  + (size_t)rm * 128 + t] = hrow[273 + t];
        out[O_VAR_V + (size_t)rm * 128 + t] = expf(hrow[401 + t]);
    } else if (t == 128) {
        out[O_MASK + rm] = hrow[0];
    } else if (t == 129 || t == 130) {
        int boff = (t == 129) ? 1 : 265;
        size_t oo = ((t == 129) ? O_PI_M : O_PI_V) + (size_t)rm * 8;
        float v[8], mx = -1e30f;
#pragma unroll
        for (int j = 0; j < 8; ++j) { v[j] = hrow[boff + j]; mx = fmaxf(mx, v[j]); }
        float sm = 0.f;
#pragma unroll
        for (int j = 0; j < 8; ++j) { v[j] = expf(v[j] - mx); sm += v[j]; }
        float inv = 1.f / sm;
#pragma unroll
        for (int j = 0; j < 8; ++j) out[oo + j] = v[j] * inv;
    }
}

// ---------------- launcher ----------------
extern "C" void kernel_launch(void* const* d_in, const int* in_sizes, int n_in,
                              void* d_out, int out_size, void* d_ws, size_t ws_size,
                              hipStream_t stream) {
    (void)in_sizes; (void)n_in; (void)out_size; (void)ws_size;
    const float* input   = (const float*)d_in[0];
    const float* targets = (const float*)d_in[1];
    const float* W_emb   = (const float*)d_in[2];
    const float* b_emb   = (const float*)d_in[3];
    const float* sos     = (const float*)d_in[4];
    const float* Wqkv    = (const float*)d_in[5];
    const float* bqkv    = (const float*)d_in[6];
    const float* Wo      = (const float*)d_in[7];
    const float* bo      = (const float*)d_in[8];
    const float* W1      = (const float*)d_in[9];
    const float* b1      = (const float*)d_in[10];
    const float* W2      = (const float*)d_in[11];
    const float* b2      = (const float*)d_in[12];
    const float* g1      = (const float*)d_in[13];
    const float* be1     = (const float*)d_in[14];
    const float* g2      = (const float*)d_in[15];
    const float* be2     = (const float*)d_in[16];
    const float* Wm      = (const float*)d_in[17];
    const float* bm      = (const float*)d_in[18];
    const float* Wpi_m   = (const float*)d_in[19];
    const float* bpi_m   = (const float*)d_in[20];
    const float* Wmu_m   = (const float*)d_in[21];
    const float* bmu_m   = (const float*)d_in[22];
    const float* Wsg_m   = (const float*)d_in[23];
    const float* bsg_m   = (const float*)d_in[24];
    const float* Wpi_v   = (const float*)d_in[25];
    const float* bpi_v   = (const float*)d_in[26];
    const float* Wmu_v   = (const float*)d_in[27];
    const float* bmu_v   = (const float*)d_in[28];
    const float* Wsg_v   = (const float*)d_in[29];
    const float* bsg_v   = (const float*)d_in[30];
    float* out = (float*)d_out;

    char* ws = (char*)d_ws;                            // ~167 MB total
    float* pe      = (float*)(ws + 0);                 // 0.5 MB
    bf16*  xin     = (bf16*)(ws + 524288);             // 4.72 MB
    bf16*  wemb    = (bf16*)(ws + 5242880);            // 1.18 MB
    bf16*  whead   = (bf16*)(ws + 6422528);            // 1.31 MB (640 rows)
    float* bhead   = (float*)(ws + 7733248);           // 2.5 KB
    bf16*  xb      = (bf16*)(ws + 24513024);           // 8.4 MB (bf16 residual stream + GEMM input)
    bf16*  qkvb    = (bf16*)(ws + 32901632);           // 25.2 MB
    bf16*  ob      = (bf16*)(ws + 58067456);           // 8.4 MB (attn out, reused as FF hidden)
    bf16*  tmpb    = (bf16*)(ws + 66456064);           // 8.4 MB (gemm-out bf16, pre-LN)
    bf16*  wqb_all = (bf16*)(ws + 83233280);           // 37.7 MB (6 layers)
    bf16*  wob_all = (bf16*)(ws + 120982016);          // 12.6 MB
    bf16*  w1b_all = (bf16*)(ws + 133564928);          // 12.6 MB
    bf16*  w2b_all = (bf16*)(ws + 146147840);          // 12.6 MB
    float* hout    = (float*)(ws + 158730752);         // 8.6 MB

    prep_cvt_kernel<<<6497, 256, 0, stream>>>(input, targets, sos, W_emb,
                                              Wm, Wpi_m, Wmu_m, Wsg_m, Wpi_v, Wmu_v, Wsg_v,
                                              bm, bpi_m, bmu_m, bsg_m, bpi_v, bmu_v, bsg_v,
                                              Wqkv, Wo, W1, W2,
                                              pe, xin, wemb, whead, bhead,
                                              wqb_all, wob_all, w1b_all, w2b_all);
    // x = XIN @ Wemb^T + b + pe -> xb (bf16 residual stream); K=576 -> BK64 CFG=1
    gemm_bt<4, 1><<<dim3(8, 32, 1), 512, 0, stream>>>(xin, wemb, nullptr, xb, b_emb, pe,
                                                      4096, 1024, 576, 576, 576, 1024, 0, 0);
    for (int l = 0; l < 6; ++l) {
        const bf16* wqb = wqb_all + (size_t)l * 3145728;
        const bf16* wob = wob_all + (size_t)l * 1048576;
        const bf16* w1b = w1b_all + (size_t)l * 1048576;
        const bf16* w2b = w2b_all + (size_t)l * 1048576;
        // qkv = x @ Wqkv^T + b  (bf16 out) -- 768 blocks, single-buffer, 4 blocks/CU
        gemm_bt<0, 0><<<dim3(24, 32, 1), 256, 0, stream>>>(xb, wqb, nullptr, qkvb, bqkv + l * 3072,
                                                           nullptr, 4096, 3072, 1024, 1024, 1024, 3072, 0, 0);
        attn_fused<<<512, 256, 0, stream>>>(qkvb, ob);
        // go = o @ Wo^T + bo (bf16); residual folded into ln_res -- BK128 dbuf
        gemm_bt<0, 2><<<dim3(8, 32, 1), 512, 0, stream>>>(ob, wob, nullptr, tmpb, bo + l * 1024,
                                                          nullptr, 4096, 1024, 1024, 1024, 1024, 1024, 0, 0);
        ln_res_kernel<<<2048, 256, 0, stream>>>(tmpb, xb, g1 + l * 1024, be1 + l * 1024, xb);
        // t1 = relu(x @ W1^T + b1) (bf16, reuse ob)
        gemm_bt<1, 2><<<dim3(8, 32, 1), 512, 0, stream>>>(xb, w1b, nullptr, ob, b1 + l * 1024,
                                                          nullptr, 4096, 1024, 1024, 1024, 1024, 1024, 0, 0);
        // go = t1 @ W2^T + b2 (bf16); residual folded into ln_res
        gemm_bt<0, 2><<<dim3(8, 32, 1), 512, 0, stream>>>(ob, w2b, nullptr, tmpb, b2 + l * 1024,
                                                          nullptr, 4096, 1024, 1024, 1024, 1024, 1024, 0, 0);
        ln_res_kernel<<<2048, 256, 0, stream>>>(tmpb, xb, g2 + l * 1024, be2 + l * 1024, xb);
    }
    // heads: per-batch M=127 rows of x -> hout (B,127,529) -- grid 5/z, swizzle auto-skipped
    gemm_bt<3, 2><<<dim3(5, 1, 32), 512, 0, stream>>>(xb, whead, hout, nullptr, bhead, nullptr,
                                                      127, 529, 1024, 1024, 1024, 529, 131072LL, 67183LL);
    finalize_kernel<<<4064, 256, 0, stream>>>(hout, out);
}